// Round 4
// baseline (1159.909 us; speedup 1.0000x reference)
//
#include <hip/hip_runtime.h>
#include <math.h>

#define T_TOK 8192
#define HDIM 2048
#define IDIM 1024
#define NE 8

typedef __attribute__((ext_vector_type(8))) short short8;
typedef __attribute__((ext_vector_type(4))) float f32x4;
typedef unsigned short u16;

__device__ inline u16 f2bf(float f) {
  unsigned u = __builtin_bit_cast(unsigned, f);
  u += 0x7fffu + ((u >> 16) & 1);  // RNE
  return (u16)(u >> 16);
}

// LDS tile: [row][40 u16] (80 B rows, b128-aligned granules). Granule g
// (k=8g..8g+7) of row r lives at position g ^ ((r>>3)&3)  -> ~2-way banks
// on b128 reads, b128 writes and 8-B half-granule writes.
__device__ inline int swz(int row, int g) { return row * 40 + 8 * (g ^ ((row >> 3) & 3)); }

// ---------------- K0: zero out region + counters ----------------
__global__ __launch_bounds__(256) void k0_zero(float* __restrict__ out,
                                               unsigned* __restrict__ meta) {
  size_t i = (size_t)blockIdx.x * blockDim.x + threadIdx.x;
  size_t n4 = (size_t)T_TOK * HDIM / 4;
  float4* o4 = (float4*)out;
  float4 z = make_float4(0.f, 0.f, 0.f, 0.f);
  for (size_t p = i; p < n4; p += (size_t)gridDim.x * blockDim.x) o4[p] = z;
  if (blockIdx.x == 0 && threadIdx.x < 24) meta[threadIdx.x] = 0;  // cnt+cursor+offsets
}

// ---------------- KX: x fp32 -> bf16 ----------------
__global__ __launch_bounds__(256) void kx_cvt(const float* __restrict__ x, u16* __restrict__ xb) {
  size_t total = (size_t)T_TOK * HDIM;
  size_t stride = (size_t)gridDim.x * 256 * 8;
  for (size_t i = ((size_t)blockIdx.x * 256 + threadIdx.x) * 8; i < total; i += stride) {
    float4 v0 = *(const float4*)(x + i);
    float4 v1 = *(const float4*)(x + i + 4);
    short8 o;
    o[0] = f2bf(v0.x); o[1] = f2bf(v0.y); o[2] = f2bf(v0.z); o[3] = f2bf(v0.w);
    o[4] = f2bf(v1.x); o[5] = f2bf(v1.y); o[6] = f2bf(v1.z); o[7] = f2bf(v1.w);
    *(short8*)(xb + i) = o;
  }
}

// ---------------- K1: router ----------------
__global__ __launch_bounds__(256) void k1_router(const float* __restrict__ x,
                                                 const float* __restrict__ wgate,
                                                 float* __restrict__ logits_out,
                                                 char* __restrict__ sel,
                                                 float* __restrict__ wt,
                                                 unsigned* __restrict__ cnt) {
  int wave = threadIdx.x >> 6;
  int lane = threadIdx.x & 63;
  int t = blockIdx.x * 4 + wave;
  float acc[NE];
#pragma unroll
  for (int e = 0; e < NE; ++e) acc[e] = 0.f;
  const float4* xr = (const float4*)(x + (size_t)t * HDIM);
#pragma unroll
  for (int c = 0; c < HDIM / 256; ++c) {
    float4 xv = xr[c * 64 + lane];
    int h = (c * 64 + lane) * 4;
    const float xs[4] = {xv.x, xv.y, xv.z, xv.w};
#pragma unroll
    for (int j = 0; j < 4; ++j) {
      const float* wrow = wgate + (size_t)(h + j) * NE;
#pragma unroll
      for (int e = 0; e < NE; ++e) acc[e] += xs[j] * wrow[e];
    }
  }
#pragma unroll
  for (int e = 0; e < NE; ++e) {
    float v = acc[e];
#pragma unroll
    for (int off = 32; off; off >>= 1) v += __shfl_xor(v, off, 64);
    acc[e] = v;
  }
  if (lane == 0) {
    float m = acc[0];
#pragma unroll
    for (int e = 0; e < NE; ++e) {
      logits_out[(size_t)t * NE + e] = acc[e];
      m = fmaxf(m, acc[e]);
    }
    float p[NE];
#pragma unroll
    for (int e = 0; e < NE; ++e) p[e] = expf(acc[e] - m);
    int b0 = 0;
    float v0 = p[0];
#pragma unroll
    for (int e = 1; e < NE; ++e)
      if (p[e] > v0) { v0 = p[e]; b0 = e; }
    int b1 = -1;
    float v1 = -1.f;
#pragma unroll
    for (int e = 0; e < NE; ++e)
      if (e != b0 && p[e] > v1) { v1 = p[e]; b1 = e; }
    float denom = v0 + v1;
    sel[t * 2 + 0] = (char)b0;
    sel[t * 2 + 1] = (char)b1;
    wt[t * 2 + 0] = v0 / denom;
    wt[t * 2 + 1] = v1 / denom;
    atomicAdd(&cnt[b0], 1u);
    atomicAdd(&cnt[b1], 1u);
  }
}

// ---------------- K2 / K3 ----------------
__global__ void k2_prefix(const unsigned* __restrict__ cnt, unsigned* __restrict__ offsets,
                          unsigned* __restrict__ cursor) {
  if (threadIdx.x == 0) {
    unsigned s = 0;
    for (int e = 0; e < NE; ++e) {
      offsets[e] = s;
      s += cnt[e];
    }
  }
  if (threadIdx.x < NE) cursor[threadIdx.x] = 0;
}

__global__ __launch_bounds__(256) void k3_assign(const char* __restrict__ sel,
                                                 const float* __restrict__ wt,
                                                 const unsigned* __restrict__ offsets,
                                                 unsigned* __restrict__ cursor,
                                                 int* __restrict__ slot_token,
                                                 float* __restrict__ slot_w) {
  int t = blockIdx.x * 256 + threadIdx.x;
#pragma unroll
  for (int k = 0; k < 2; ++k) {
    int e = sel[t * 2 + k];
    unsigned p = atomicAdd(&cursor[e], 1u);
    unsigned s = offsets[e] + p;
    slot_token[s] = t;
    slot_w[s] = wt[t * 2 + k];
  }
}

// ---------------- K4: MFMA gate+up + silu -> bf16 act ----------------
// tile 128m x 64n, 4 waves (64x32 each), K-step 32
template <bool XBF>
__global__ __launch_bounds__(256) void k4_gateup(
    const float* __restrict__ x, const u16* __restrict__ xb,
    const float* __restrict__ wg_all, const float* __restrict__ wu_all,
    const int* __restrict__ slot_token, const unsigned* __restrict__ offsets,
    const unsigned* __restrict__ cnt, u16* __restrict__ act) {
  int e = blockIdx.z;
  unsigned n = cnt[e];
  unsigned row0 = blockIdx.x * 128;
  if (row0 >= n) return;
  unsigned base = offsets[e];
  int col0 = blockIdx.y * 64;
  const float* Wg = wg_all + (size_t)e * HDIM * IDIM;
  const float* Wu = wu_all + (size_t)e * HDIM * IDIM;

  __shared__ u16 lA[128 * 40];
  __shared__ u16 lB[2][64 * 40];

  int tid = threadIdx.x;

  // A role: thread copies 2 granules of row ar (granules 2*acp, 2*acp+1)
  int ar = tid & 127, acp = tid >> 7;
  unsigned grow = row0 + (unsigned)ar;
  unsigned slot = base + (grow < n ? grow : 0);
  int tok = slot_token[slot];
  const u16* asrc_b = xb + (size_t)tok * HDIM + 16 * acp;
  const float* asrc_f = x + (size_t)tok * HDIM + 16 * acp;
  int aoff0 = swz(ar, 2 * acp), aoff1 = swz(ar, 2 * acp + 1);

  // B role: thread owns 4k x 4n micro-tile of one matrix
  int mat = tid >> 7;
  int tt = tid & 127;
  int bka = tt >> 4;  // k = 4*bka .. 4*bka+3
  int bn0 = (tt & 15) * 4;
  const float* bsrc = (mat ? Wu : Wg) + (size_t)(4 * bka) * IDIM + col0 + bn0;
  u16* bdst = lB[mat];
  int bg_ = bka >> 1, bh = bka & 1;
  int boffs[4];
#pragma unroll
  for (int i = 0; i < 4; ++i) {
    int nn = bn0 + i;
    boffs[i] = nn * 40 + 8 * (bg_ ^ ((nn >> 3) & 3)) + 4 * bh;
  }

  int wid = tid >> 6, lane = tid & 63;
  int wr = wid >> 1, wc = wid & 1;
  int lr = lane & 15, g = lane >> 4;
  int afo[4], bfo[2];
#pragma unroll
  for (int mf = 0; mf < 4; ++mf) afo[mf] = swz(wr * 64 + mf * 16 + lr, g);
#pragma unroll
  for (int nf = 0; nf < 2; ++nf) bfo[nf] = swz(wc * 32 + nf * 16 + lr, g);

  f32x4 accg[4][2] = {};
  f32x4 accu[4][2] = {};

  short8 pa0, pa1;
  float4 paf[4];
  float4 pb[4];

  auto do_load = [&](int k0) {
    if (XBF) {
      pa0 = *(const short8*)(asrc_b + k0);
      pa1 = *(const short8*)(asrc_b + k0 + 8);
    } else {
#pragma unroll
      for (int d = 0; d < 4; ++d) paf[d] = *(const float4*)(asrc_f + k0 + 4 * d);
    }
#pragma unroll
    for (int r = 0; r < 4; ++r) pb[r] = *(const float4*)(bsrc + (size_t)(k0 + r) * IDIM);
  };

  do_load(0);
  const int NK = HDIM / 32;
  for (int kt = 0; kt < NK; ++kt) {
    __syncthreads();
    short8 a0, a1;
    if (XBF) {
      a0 = pa0;
      a1 = pa1;
    } else {
      a0[0] = f2bf(paf[0].x); a0[1] = f2bf(paf[0].y); a0[2] = f2bf(paf[0].z); a0[3] = f2bf(paf[0].w);
      a0[4] = f2bf(paf[1].x); a0[5] = f2bf(paf[1].y); a0[6] = f2bf(paf[1].z); a0[7] = f2bf(paf[1].w);
      a1[0] = f2bf(paf[2].x); a1[1] = f2bf(paf[2].y); a1[2] = f2bf(paf[2].z); a1[3] = f2bf(paf[2].w);
      a1[4] = f2bf(paf[3].x); a1[5] = f2bf(paf[3].y); a1[6] = f2bf(paf[3].z); a1[7] = f2bf(paf[3].w);
    }
    *(short8*)&lA[aoff0] = a0;
    *(short8*)&lA[aoff1] = a1;
    {
      float vv[4][4] = {{pb[0].x, pb[0].y, pb[0].z, pb[0].w},
                        {pb[1].x, pb[1].y, pb[1].z, pb[1].w},
                        {pb[2].x, pb[2].y, pb[2].z, pb[2].w},
                        {pb[3].x, pb[3].y, pb[3].z, pb[3].w}};
#pragma unroll
      for (int i = 0; i < 4; ++i) {
        ushort4 w4 = make_ushort4(f2bf(vv[0][i]), f2bf(vv[1][i]), f2bf(vv[2][i]), f2bf(vv[3][i]));
        *(ushort4*)&bdst[boffs[i]] = w4;
      }
    }
    __syncthreads();
    if (kt + 1 < NK) do_load((kt + 1) * 32);

    short8 af[4];
#pragma unroll
    for (int mf = 0; mf < 4; ++mf) af[mf] = *(const short8*)&lA[afo[mf]];
#pragma unroll
    for (int nf = 0; nf < 2; ++nf) {
      short8 bgf = *(const short8*)&lB[0][bfo[nf]];
      short8 buf = *(const short8*)&lB[1][bfo[nf]];
#pragma unroll
      for (int mf = 0; mf < 4; ++mf) {
        accg[mf][nf] = __builtin_amdgcn_mfma_f32_16x16x32_bf16(af[mf], bgf, accg[mf][nf], 0, 0, 0);
        accu[mf][nf] = __builtin_amdgcn_mfma_f32_16x16x32_bf16(af[mf], buf, accu[mf][nf], 0, 0, 0);
      }
    }
  }

  unsigned rows_left = n - row0;
#pragma unroll
  for (int mf = 0; mf < 4; ++mf)
#pragma unroll
    for (int nf = 0; nf < 2; ++nf)
#pragma unroll
      for (int j = 0; j < 4; ++j) {
        int rin = wr * 64 + mf * 16 + 4 * g + j;
        if ((unsigned)rin < rows_left) {
          size_t s = base + row0 + rin;
          int col = col0 + wc * 32 + nf * 16 + lr;
          float gg = accg[mf][nf][j];
          float uu = accu[mf][nf][j];
          float v = (gg / (1.f + expf(-gg))) * uu;
          act[s * IDIM + col] = f2bf(v);
        }
      }
}

// ---------------- K5: MFMA down + weighted atomic combine ----------------
// tile 128m x 128n, 4 waves (64x64 each), K-step 32
__global__ __launch_bounds__(256) void k5_down(
    const u16* __restrict__ act, const float* __restrict__ wd_all,
    const int* __restrict__ slot_token, const float* __restrict__ slot_w,
    const unsigned* __restrict__ offsets, const unsigned* __restrict__ cnt,
    float* __restrict__ out) {
  int e = blockIdx.z;
  unsigned n = cnt[e];
  unsigned row0 = blockIdx.x * 128;
  if (row0 >= n) return;
  unsigned base = offsets[e];
  int col0 = blockIdx.y * 128;
  const float* Wd = wd_all + (size_t)e * IDIM * HDIM;

  __shared__ u16 lA[128 * 40];
  __shared__ u16 lBd[128 * 40];

  int tid = threadIdx.x;

  // A role (act rows are contiguous slots)
  int ar = tid & 127, acp = tid >> 7;
  unsigned grow = row0 + (unsigned)ar;
  unsigned slot = base + (grow < n ? grow : 0);
  const u16* asrc = act + (size_t)slot * IDIM + 16 * acp;
  int aoff0 = swz(ar, 2 * acp), aoff1 = swz(ar, 2 * acp + 1);

  // B role: 4k x 4n micro-tile
  int bka = (tid >> 5) & 7;
  int bn0 = (tid & 31) * 4;
  const float* bsrc = Wd + (size_t)(4 * bka) * HDIM + col0 + bn0;
  int bg_ = bka >> 1, bh = bka & 1;
  int boffs[4];
#pragma unroll
  for (int i = 0; i < 4; ++i) {
    int nn = bn0 + i;
    boffs[i] = nn * 40 + 8 * (bg_ ^ ((nn >> 3) & 3)) + 4 * bh;
  }

  int wid = tid >> 6, lane = tid & 63;
  int wr = wid >> 1, wc = wid & 1;
  int lr = lane & 15, g = lane >> 4;
  int afo[4], bfo[4];
#pragma unroll
  for (int mf = 0; mf < 4; ++mf) afo[mf] = swz(wr * 64 + mf * 16 + lr, g);
#pragma unroll
  for (int nf = 0; nf < 4; ++nf) bfo[nf] = swz(wc * 64 + nf * 16 + lr, g);

  f32x4 acc[4][4] = {};

  short8 pa0, pa1;
  float4 pb[4];
  auto do_load = [&](int k0) {
    pa0 = *(const short8*)(asrc + k0);
    pa1 = *(const short8*)(asrc + k0 + 8);
#pragma unroll
    for (int r = 0; r < 4; ++r) pb[r] = *(const float4*)(bsrc + (size_t)(k0 + r) * HDIM);
  };

  do_load(0);
  const int NK = IDIM / 32;
  for (int kt = 0; kt < NK; ++kt) {
    __syncthreads();
    *(short8*)&lA[aoff0] = pa0;
    *(short8*)&lA[aoff1] = pa1;
    {
      float vv[4][4] = {{pb[0].x, pb[0].y, pb[0].z, pb[0].w},
                        {pb[1].x, pb[1].y, pb[1].z, pb[1].w},
                        {pb[2].x, pb[2].y, pb[2].z, pb[2].w},
                        {pb[3].x, pb[3].y, pb[3].z, pb[3].w}};
#pragma unroll
      for (int i = 0; i < 4; ++i) {
        ushort4 w4 = make_ushort4(f2bf(vv[0][i]), f2bf(vv[1][i]), f2bf(vv[2][i]), f2bf(vv[3][i]));
        *(ushort4*)&lBd[boffs[i]] = w4;
      }
    }
    __syncthreads();
    if (kt + 1 < NK) do_load((kt + 1) * 32);

    short8 af[4];
#pragma unroll
    for (int mf = 0; mf < 4; ++mf) af[mf] = *(const short8*)&lA[afo[mf]];
#pragma unroll
    for (int nf = 0; nf < 4; ++nf) {
      short8 bd = *(const short8*)&lBd[bfo[nf]];
#pragma unroll
      for (int mf = 0; mf < 4; ++mf)
        acc[mf][nf] = __builtin_amdgcn_mfma_f32_16x16x32_bf16(af[mf], bd, acc[mf][nf], 0, 0, 0);
    }
  }

  unsigned rows_left = n - row0;
#pragma unroll
  for (int mf = 0; mf < 4; ++mf)
#pragma unroll
    for (int j = 0; j < 4; ++j) {
      int rin = wr * 64 + mf * 16 + 4 * g + j;
      if ((unsigned)rin < rows_left) {
        size_t s = base + row0 + rin;
        int token = slot_token[s];
        float w = slot_w[s];
        float* orow = out + (size_t)token * HDIM + col0 + wc * 64 + lr;
#pragma unroll
        for (int nf = 0; nf < 4; ++nf) atomicAdd(&orow[nf * 16], w * acc[mf][nf][j]);
      }
    }
}

extern "C" void kernel_launch(void* const* d_in, const int* in_sizes, int n_in,
                              void* d_out, int out_size, void* d_ws, size_t ws_size,
                              hipStream_t stream) {
  const float* x = (const float*)d_in[0];
  const float* wgate = (const float*)d_in[1];
  const float* wg = (const float*)d_in[2];
  const float* wu = (const float*)d_in[3];
  const float* wd = (const float*)d_in[4];
  float* out = (float*)d_out;
  float* logits = out + (size_t)T_TOK * HDIM;

  char* ws = (char*)d_ws;
  unsigned* meta = (unsigned*)ws;  // cnt[8] @0, cursor[8] @32, offsets[8] @64 (u32 idx)
  unsigned* cnt = meta + 0;
  unsigned* cursor = meta + 8;
  unsigned* offsets = meta + 16;
  int* slot_token = (int*)(ws + 256);     // 64 KB
  float* slot_w = (float*)(ws + 65792);   // 64 KB -> ends 131328

  // Tiers (proven: ws_size >= 33,817,600 from r2/r3; big tier is a probe)
  const size_t XBF_OFF = 132096;                        // 1024-aligned
  const size_t ACT_BIG = XBF_OFF + (size_t)T_TOK * HDIM * 2;   // 33,686,528
  const size_t NEED_BIG = ACT_BIG + (size_t)2 * T_TOK * IDIM * 2;  // 67,240,960
  const size_t ACT_SMALL = 213504;
  const size_t NEED_SMALL = ACT_SMALL + (size_t)2 * T_TOK * IDIM * 2;  // 33,767,936
  if (ws_size < NEED_SMALL) return;  // loud failure
  bool big = ws_size >= NEED_BIG;

  u16* xbf = (u16*)(ws + XBF_OFF);
  u16* act = (u16*)(ws + (big ? ACT_BIG : ACT_SMALL));
  // sel/wt are dead before k4 writes act -> stash them inside the act region
  // (big tier) or in their own slots (small tier).
  char* sel;
  float* wt;
  if (big) {
    sel = (char*)act;
    wt = (float*)((char*)act + 16384);
  } else {
    sel = ws + 131328;
    wt = (float*)(ws + 147712);
  }

  k0_zero<<<2048, 256, 0, stream>>>(out, meta);
  if (big) kx_cvt<<<2048, 256, 0, stream>>>(x, xbf);
  k1_router<<<T_TOK / 4, 256, 0, stream>>>(x, wgate, logits, sel, wt, cnt);
  k2_prefix<<<1, 64, 0, stream>>>(cnt, offsets, cursor);
  k3_assign<<<T_TOK / 256, 256, 0, stream>>>(sel, wt, offsets, cursor, slot_token, slot_w);
  if (big)
    k4_gateup<true><<<dim3(T_TOK / 128, IDIM / 64, NE), 256, 0, stream>>>(
        x, xbf, wg, wu, slot_token, offsets, cnt, act);
  else
    k4_gateup<false><<<dim3(T_TOK / 128, IDIM / 64, NE), 256, 0, stream>>>(
        x, xbf, wg, wu, slot_token, offsets, cnt, act);
  k5_down<<<dim3(T_TOK / 128, HDIM / 128, NE), 256, 0, stream>>>(
      act, wd, slot_token, slot_w, offsets, cnt, out);
}

// Round 5
// 1000.825 us; speedup vs baseline: 1.1590x; 1.1590x over previous
//
#include <hip/hip_runtime.h>
#include <math.h>

#define T_TOK 8192
#define HDIM 2048
#define IDIM 1024
#define NE 8

typedef __attribute__((ext_vector_type(8))) short short8;
typedef __attribute__((ext_vector_type(4))) float f32x4;
typedef unsigned short u16;

__device__ inline u16 f2bf(float f) {
  unsigned u = __builtin_bit_cast(unsigned, f);
  u += 0x7fffu + ((u >> 16) & 1);  // RNE
  return (u16)(u >> 16);
}

// async global->LDS, 16B per lane. LDS dest = wave-uniform base + lane*16.
__device__ inline void gl_lds(const u16* g, u16* l) {
  __builtin_amdgcn_global_load_lds((const __attribute__((address_space(1))) unsigned int*)g,
                                   (__attribute__((address_space(3))) unsigned int*)l, 16, 0, 0);
}

// A/B bf16 LDS tiles are [row][32] (64B rows), stored with chunk swizzle applied
// on the GLOBAL source address: chunk position p holds global chunk p ^ s(row),
// s(row) = (row>>1)&3. Frag read of granule g: offset row*32 + 8*(g ^ s(row))
// -> 16-lane group covers 8 distinct banks = 2-way (free).
__device__ inline int rswz(int row, int g) { return row * 32 + 8 * (g ^ ((row >> 1) & 3)); }

// tier-2 fp32-B LDS: [n][40] u16 rows, granule swizzle g ^ ((n>>3)&3) (R4-proven).
__device__ inline int bswz40(int n, int g) { return n * 40 + 8 * (g ^ ((n >> 3) & 3)); }

// ---------------- K0: zero out region + counters ----------------
__global__ __launch_bounds__(256) void k0_zero(float* __restrict__ out,
                                               unsigned* __restrict__ meta) {
  size_t i = (size_t)blockIdx.x * blockDim.x + threadIdx.x;
  size_t n4 = (size_t)T_TOK * HDIM / 4;
  float4* o4 = (float4*)out;
  float4 z = make_float4(0.f, 0.f, 0.f, 0.f);
  for (size_t p = i; p < n4; p += (size_t)gridDim.x * blockDim.x) o4[p] = z;
  if (blockIdx.x == 0 && threadIdx.x < 24) meta[threadIdx.x] = 0;
}

// ---------------- KX: x fp32 -> bf16 ----------------
__global__ __launch_bounds__(256) void kx_cvt(const float* __restrict__ x, u16* __restrict__ xb) {
  size_t total = (size_t)T_TOK * HDIM;
  size_t stride = (size_t)gridDim.x * 256 * 8;
  for (size_t i = ((size_t)blockIdx.x * 256 + threadIdx.x) * 8; i < total; i += stride) {
    float4 v0 = *(const float4*)(x + i);
    float4 v1 = *(const float4*)(x + i + 4);
    short8 o;
    o[0] = f2bf(v0.x); o[1] = f2bf(v0.y); o[2] = f2bf(v0.z); o[3] = f2bf(v0.w);
    o[4] = f2bf(v1.x); o[5] = f2bf(v1.y); o[6] = f2bf(v1.z); o[7] = f2bf(v1.w);
    *(short8*)(xb + i) = o;
  }
}

// ---------------- KT: weight transpose + cvt: dst[n][k] = bf16(src[k][n]) ----------------
__global__ __launch_bounds__(256) void kt_transpose(const float* __restrict__ src,
                                                    u16* __restrict__ dst, int K, int N) {
  __shared__ u16 t[64][72];
  int e = blockIdx.z;
  src += (size_t)e * K * N;
  dst += (size_t)e * K * N;
  int nb = blockIdx.x * 64, kb = blockIdx.y * 64;
  int tid = threadIdx.x;
  int lk = tid >> 4, ln = (tid & 15) * 4;
#pragma unroll
  for (int p = 0; p < 4; ++p) {
    int k = lk + 16 * p;
    float4 v = *(const float4*)(src + (size_t)(kb + k) * N + nb + ln);
    t[ln + 0][k] = f2bf(v.x);
    t[ln + 1][k] = f2bf(v.y);
    t[ln + 2][k] = f2bf(v.z);
    t[ln + 3][k] = f2bf(v.w);
  }
  __syncthreads();
  int n = tid >> 2, c = tid & 3;
  short8 o0 = *(const short8*)&t[n][c * 16];
  short8 o1 = *(const short8*)&t[n][c * 16 + 8];
  u16* d = dst + (size_t)(nb + n) * K + kb + c * 16;
  *(short8*)d = o0;
  *(short8*)(d + 8) = o1;
}

// ---------------- K1: router ----------------
__global__ __launch_bounds__(256) void k1_router(const float* __restrict__ x,
                                                 const float* __restrict__ wgate,
                                                 float* __restrict__ logits_out,
                                                 char* __restrict__ sel,
                                                 float* __restrict__ wt,
                                                 unsigned* __restrict__ cnt) {
  int wave = threadIdx.x >> 6;
  int lane = threadIdx.x & 63;
  int t = blockIdx.x * 4 + wave;
  float acc[NE];
#pragma unroll
  for (int e = 0; e < NE; ++e) acc[e] = 0.f;
  const float4* xr = (const float4*)(x + (size_t)t * HDIM);
#pragma unroll
  for (int c = 0; c < HDIM / 256; ++c) {
    float4 xv = xr[c * 64 + lane];
    int h = (c * 64 + lane) * 4;
    const float xs[4] = {xv.x, xv.y, xv.z, xv.w};
#pragma unroll
    for (int j = 0; j < 4; ++j) {
      const float* wrow = wgate + (size_t)(h + j) * NE;
#pragma unroll
      for (int e = 0; e < NE; ++e) acc[e] += xs[j] * wrow[e];
    }
  }
#pragma unroll
  for (int e = 0; e < NE; ++e) {
    float v = acc[e];
#pragma unroll
    for (int off = 32; off; off >>= 1) v += __shfl_xor(v, off, 64);
    acc[e] = v;
  }
  if (lane == 0) {
    float m = acc[0];
#pragma unroll
    for (int e = 0; e < NE; ++e) {
      logits_out[(size_t)t * NE + e] = acc[e];
      m = fmaxf(m, acc[e]);
    }
    float p[NE];
#pragma unroll
    for (int e = 0; e < NE; ++e) p[e] = expf(acc[e] - m);
    int b0 = 0;
    float v0 = p[0];
#pragma unroll
    for (int e = 1; e < NE; ++e)
      if (p[e] > v0) { v0 = p[e]; b0 = e; }
    int b1 = -1;
    float v1 = -1.f;
#pragma unroll
    for (int e = 0; e < NE; ++e)
      if (e != b0 && p[e] > v1) { v1 = p[e]; b1 = e; }
    float denom = v0 + v1;
    sel[t * 2 + 0] = (char)b0;
    sel[t * 2 + 1] = (char)b1;
    wt[t * 2 + 0] = v0 / denom;
    wt[t * 2 + 1] = v1 / denom;
    atomicAdd(&cnt[b0], 1u);
    atomicAdd(&cnt[b1], 1u);
  }
}

// ---------------- K2 / K3 ----------------
__global__ void k2_prefix(const unsigned* __restrict__ cnt, unsigned* __restrict__ offsets,
                          unsigned* __restrict__ cursor) {
  if (threadIdx.x == 0) {
    unsigned s = 0;
    for (int e = 0; e < NE; ++e) {
      offsets[e] = s;
      s += cnt[e];
    }
  }
  if (threadIdx.x < NE) cursor[threadIdx.x] = 0;
}

__global__ __launch_bounds__(256) void k3_assign(const char* __restrict__ sel,
                                                 const float* __restrict__ wt,
                                                 const unsigned* __restrict__ offsets,
                                                 unsigned* __restrict__ cursor,
                                                 int* __restrict__ slot_token,
                                                 float* __restrict__ slot_w) {
  int t = blockIdx.x * 256 + threadIdx.x;
#pragma unroll
  for (int k = 0; k < 2; ++k) {
    int e = sel[t * 2 + k];
    unsigned p = atomicAdd(&cursor[e], 1u);
    unsigned s = offsets[e] + p;
    slot_token[s] = t;
    slot_w[s] = wt[t * 2 + k];
  }
}

// ---------------- K4: MFMA gate+up + silu -> bf16 act ----------------
// tile 128m x 64n, 4 waves (64x32 each), BK=32, LDS double-buffered,
// A via global_load_lds from xbf; B via gl_lds from W^T (BGL) or fp32 reg-cvt.
template <bool BGL>
__global__ __launch_bounds__(256) void k4_gateup(
    const u16* __restrict__ xb, const float* __restrict__ wg_all,
    const float* __restrict__ wu_all, const u16* __restrict__ wgT,
    const u16* __restrict__ wuT, const int* __restrict__ slot_token,
    const unsigned* __restrict__ offsets, const unsigned* __restrict__ cnt,
    u16* __restrict__ act) {
  int e = blockIdx.z;
  unsigned n = cnt[e];
  unsigned row0 = blockIdx.x * 128;
  if (row0 >= n) return;
  unsigned base = offsets[e];
  int col0 = blockIdx.y * 64;

  __shared__ __align__(16) u16 As[2][128 * 32];
  __shared__ __align__(16) u16 Bs[2][2][BGL ? 64 * 32 : 64 * 40];

  int tid = threadIdx.x;
  int w = tid >> 6, l = tid & 63;
  int wr = w >> 1, wc = w & 1;
  int lr = l & 15, g = l >> 4;

  // ---- A gl_lds setup: 2 issues/wave, 16 rows each; lane -> row aw+ (l>>2), chunk l&3
  const u16* asrc[2];
  int adst[2];
#pragma unroll
  for (int i = 0; i < 2; ++i) {
    int r = 32 * w + 16 * i + (l >> 2);
    unsigned grow = row0 + (unsigned)r;
    unsigned slot = base + (grow < n ? grow : 0);
    int chunk = (l & 3) ^ ((r >> 1) & 3);
    asrc[i] = xb + (size_t)slot_token[slot] * HDIM + 8 * chunk;
    adst[i] = (32 * w + 16 * i) * 32;
  }

  // ---- B setup
  // BGL: 1 issue/wave/matrix, rows (cols n) 16w..16w+15
  const u16* bsrcT[2];
  int bdstT = 16 * w * 32;
  {
    int nn = 16 * w + (l >> 2);
    int chunk = (l & 3) ^ ((nn >> 1) & 3);
    bsrcT[0] = wgT + (size_t)e * HDIM * IDIM + (size_t)(col0 + nn) * HDIM + 8 * chunk;
    bsrcT[1] = wuT + (size_t)e * HDIM * IDIM + (size_t)(col0 + nn) * HDIM + 8 * chunk;
  }
  // tier-2: thread owns 4k x 4n of one matrix
  int mat = tid >> 7;
  int tt = tid & 127;
  int bka = tt >> 4;
  int bn0 = (tt & 15) * 4;
  const float* bsrcF = (mat ? wu_all : wg_all) + (size_t)e * HDIM * IDIM +
                       (size_t)(4 * bka) * IDIM + col0 + bn0;
  int boffs[4];
#pragma unroll
  for (int i = 0; i < 4; ++i)
    boffs[i] = bswz40(bn0 + i, bka >> 1) + 4 * (bka & 1);

  // frag read offsets
  int afo[4], bfo[2];
#pragma unroll
  for (int mf = 0; mf < 4; ++mf) afo[mf] = rswz(wr * 64 + mf * 16 + lr, g);
#pragma unroll
  for (int nf = 0; nf < 2; ++nf) {
    int col = wc * 32 + nf * 16 + lr;
    bfo[nf] = BGL ? rswz(col, g) : bswz40(col, g);
  }

  f32x4 accg[4][2] = {};
  f32x4 accu[4][2] = {};
  float4 pb[4];

  // ---- prologue: stage tile 0 into buffer 0
  gl_lds(asrc[0], &As[0][adst[0]]);
  gl_lds(asrc[1], &As[0][adst[1]]);
  if (BGL) {
    gl_lds(bsrcT[0], &Bs[0][0][bdstT]);
    gl_lds(bsrcT[1], &Bs[0][1][bdstT]);
  } else {
#pragma unroll
    for (int r = 0; r < 4; ++r) pb[r] = *(const float4*)(bsrcF + (size_t)r * IDIM);
#pragma unroll
    for (int i = 0; i < 4; ++i) {
      ushort4 w4 = make_ushort4(f2bf(((const float*)&pb[0])[i]), f2bf(((const float*)&pb[1])[i]),
                                f2bf(((const float*)&pb[2])[i]), f2bf(((const float*)&pb[3])[i]));
      *(ushort4*)&Bs[0][mat][boffs[i]] = w4;
    }
  }
  __syncthreads();

  const int NK = HDIM / 32;
  for (int kt = 0; kt < NK; ++kt) {
    int c = kt & 1;
    if (kt + 1 < NK) {
      int k0n = (kt + 1) * 32;
      gl_lds(asrc[0] + k0n, &As[c ^ 1][adst[0]]);
      gl_lds(asrc[1] + k0n, &As[c ^ 1][adst[1]]);
      if (BGL) {
        gl_lds(bsrcT[0] + k0n, &Bs[c ^ 1][0][bdstT]);
        gl_lds(bsrcT[1] + k0n, &Bs[c ^ 1][1][bdstT]);
      } else {
#pragma unroll
        for (int r = 0; r < 4; ++r) pb[r] = *(const float4*)(bsrcF + (size_t)(k0n + r) * IDIM);
      }
    }

    short8 af[4];
#pragma unroll
    for (int mf = 0; mf < 4; ++mf) af[mf] = *(const short8*)&As[c][afo[mf]];
#pragma unroll
    for (int nf = 0; nf < 2; ++nf) {
      short8 bgf = *(const short8*)&Bs[c][0][bfo[nf]];
      short8 buf = *(const short8*)&Bs[c][1][bfo[nf]];
#pragma unroll
      for (int mf = 0; mf < 4; ++mf) {
        accg[mf][nf] = __builtin_amdgcn_mfma_f32_16x16x32_bf16(af[mf], bgf, accg[mf][nf], 0, 0, 0);
        accu[mf][nf] = __builtin_amdgcn_mfma_f32_16x16x32_bf16(af[mf], buf, accu[mf][nf], 0, 0, 0);
      }
    }

    if (!BGL && kt + 1 < NK) {
#pragma unroll
      for (int i = 0; i < 4; ++i) {
        ushort4 w4 = make_ushort4(f2bf(((const float*)&pb[0])[i]), f2bf(((const float*)&pb[1])[i]),
                                  f2bf(((const float*)&pb[2])[i]), f2bf(((const float*)&pb[3])[i]));
        *(ushort4*)&Bs[c ^ 1][mat][boffs[i]] = w4;
      }
    }
    __syncthreads();
  }

  unsigned rows_left = n - row0;
#pragma unroll
  for (int mf = 0; mf < 4; ++mf)
#pragma unroll
    for (int nf = 0; nf < 2; ++nf)
#pragma unroll
      for (int j = 0; j < 4; ++j) {
        int rin = wr * 64 + mf * 16 + 4 * g + j;
        if ((unsigned)rin < rows_left) {
          size_t s = base + row0 + rin;
          int col = col0 + wc * 32 + nf * 16 + lr;
          float gg = accg[mf][nf][j];
          float uu = accu[mf][nf][j];
          float v = (gg / (1.f + expf(-gg))) * uu;
          act[s * IDIM + col] = f2bf(v);
        }
      }
}

// ---------------- K5: MFMA down + weighted atomic combine ----------------
// tile 128m x 128n, 4 waves (64x64 each), BK=32, same staging scheme.
template <bool BGL>
__global__ __launch_bounds__(256) void k5_down(
    const u16* __restrict__ act, const float* __restrict__ wd_all,
    const u16* __restrict__ wdT, const int* __restrict__ slot_token,
    const float* __restrict__ slot_w, const unsigned* __restrict__ offsets,
    const unsigned* __restrict__ cnt, float* __restrict__ out) {
  int e = blockIdx.z;
  unsigned n = cnt[e];
  unsigned row0 = blockIdx.x * 128;
  if (row0 >= n) return;
  unsigned base = offsets[e];
  int col0 = blockIdx.y * 128;

  __shared__ __align__(16) u16 As[2][128 * 32];
  __shared__ __align__(16) u16 Bs[2][BGL ? 128 * 32 : 128 * 40];

  int tid = threadIdx.x;
  int w = tid >> 6, l = tid & 63;
  int wr = w >> 1, wc = w & 1;
  int lr = l & 15, g = l >> 4;

  const u16* asrc[2];
  int adst[2];
#pragma unroll
  for (int i = 0; i < 2; ++i) {
    int r = 32 * w + 16 * i + (l >> 2);
    unsigned grow = row0 + (unsigned)r;
    unsigned slot = base + (grow < n ? grow : 0);
    int chunk = (l & 3) ^ ((r >> 1) & 3);
    asrc[i] = act + (size_t)slot * IDIM + 8 * chunk;
    adst[i] = (32 * w + 16 * i) * 32;
  }

  const u16* bsrcT[2];
  int bdstT[2];
#pragma unroll
  for (int i = 0; i < 2; ++i) {
    int nn = 32 * w + 16 * i + (l >> 2);
    int chunk = (l & 3) ^ ((nn >> 1) & 3);
    bsrcT[i] = wdT + (size_t)e * IDIM * HDIM + (size_t)(col0 + nn) * IDIM + 8 * chunk;
    bdstT[i] = (32 * w + 16 * i) * 32;
  }
  int bka = (tid >> 5) & 7;
  int bn0 = (tid & 31) * 4;
  const float* bsrcF = wd_all + (size_t)e * IDIM * HDIM + (size_t)(4 * bka) * HDIM + col0 + bn0;
  int boffs[4];
#pragma unroll
  for (int i = 0; i < 4; ++i)
    boffs[i] = bswz40(bn0 + i, bka >> 1) + 4 * (bka & 1);

  int afo[4], bfo[4];
#pragma unroll
  for (int mf = 0; mf < 4; ++mf) afo[mf] = rswz(wr * 64 + mf * 16 + lr, g);
#pragma unroll
  for (int nf = 0; nf < 4; ++nf) {
    int col = wc * 64 + nf * 16 + lr;
    bfo[nf] = BGL ? rswz(col, g) : bswz40(col, g);
  }

  f32x4 acc[4][4] = {};
  float4 pb[4];

  gl_lds(asrc[0], &As[0][adst[0]]);
  gl_lds(asrc[1], &As[0][adst[1]]);
  if (BGL) {
    gl_lds(bsrcT[0], &Bs[0][bdstT[0]]);
    gl_lds(bsrcT[1], &Bs[0][bdstT[1]]);
  } else {
#pragma unroll
    for (int r = 0; r < 4; ++r) pb[r] = *(const float4*)(bsrcF + (size_t)r * HDIM);
#pragma unroll
    for (int i = 0; i < 4; ++i) {
      ushort4 w4 = make_ushort4(f2bf(((const float*)&pb[0])[i]), f2bf(((const float*)&pb[1])[i]),
                                f2bf(((const float*)&pb[2])[i]), f2bf(((const float*)&pb[3])[i]));
      *(ushort4*)&Bs[0][boffs[i]] = w4;
    }
  }
  __syncthreads();

  const int NK = IDIM / 32;
  for (int kt = 0; kt < NK; ++kt) {
    int c = kt & 1;
    if (kt + 1 < NK) {
      int k0n = (kt + 1) * 32;
      gl_lds(asrc[0] + k0n, &As[c ^ 1][adst[0]]);
      gl_lds(asrc[1] + k0n, &As[c ^ 1][adst[1]]);
      if (BGL) {
        gl_lds(bsrcT[0] + k0n, &Bs[c ^ 1][bdstT[0]]);
        gl_lds(bsrcT[1] + k0n, &Bs[c ^ 1][bdstT[1]]);
      } else {
#pragma unroll
        for (int r = 0; r < 4; ++r) pb[r] = *(const float4*)(bsrcF + (size_t)(k0n + r) * HDIM);
      }
    }

    short8 af[4];
#pragma unroll
    for (int mf = 0; mf < 4; ++mf) af[mf] = *(const short8*)&As[c][afo[mf]];
#pragma unroll
    for (int nf = 0; nf < 4; ++nf) {
      short8 bd = *(const short8*)&Bs[c][bfo[nf]];
#pragma unroll
      for (int mf = 0; mf < 4; ++mf)
        acc[mf][nf] = __builtin_amdgcn_mfma_f32_16x16x32_bf16(af[mf], bd, acc[mf][nf], 0, 0, 0);
    }

    if (!BGL && kt + 1 < NK) {
#pragma unroll
      for (int i = 0; i < 4; ++i) {
        ushort4 w4 = make_ushort4(f2bf(((const float*)&pb[0])[i]), f2bf(((const float*)&pb[1])[i]),
                                  f2bf(((const float*)&pb[2])[i]), f2bf(((const float*)&pb[3])[i]));
        *(ushort4*)&Bs[c ^ 1][boffs[i]] = w4;
      }
    }
    __syncthreads();
  }

  unsigned rows_left = n - row0;
#pragma unroll
  for (int mf = 0; mf < 4; ++mf)
#pragma unroll
    for (int j = 0; j < 4; ++j) {
      int rin = wr * 64 + mf * 16 + 4 * g + j;
      if ((unsigned)rin < rows_left) {
        size_t s = base + row0 + rin;
        int token = slot_token[s];
        float wgt = slot_w[s];
        float* orow = out + (size_t)token * HDIM + col0 + wc * 64 + lr;
#pragma unroll
        for (int nf = 0; nf < 4; ++nf) atomicAdd(&orow[nf * 16], wgt * acc[mf][nf][j]);
      }
    }
}

extern "C" void kernel_launch(void* const* d_in, const int* in_sizes, int n_in,
                              void* d_out, int out_size, void* d_ws, size_t ws_size,
                              hipStream_t stream) {
  const float* x = (const float*)d_in[0];
  const float* wgate = (const float*)d_in[1];
  const float* wg = (const float*)d_in[2];
  const float* wu = (const float*)d_in[3];
  const float* wd = (const float*)d_in[4];
  float* out = (float*)d_out;
  float* logits = out + (size_t)T_TOK * HDIM;

  // layout
  const size_t XBF_OFF = 132096;
  const size_t ACT_OFF = XBF_OFF + (size_t)T_TOK * HDIM * 2;        // 33,686,528
  const size_t NEED_T2 = ACT_OFF + (size_t)2 * T_TOK * IDIM * 2;    // 67,240,960 (proven)
  const size_t WGT_OFF = NEED_T2;
  const size_t WUT_OFF = WGT_OFF + (size_t)NE * HDIM * IDIM * 2;    // +33.55MB
  const size_t WDT_OFF = WUT_OFF + (size_t)NE * HDIM * IDIM * 2;
  const size_t NEED_T3 = WDT_OFF + (size_t)NE * IDIM * HDIM * 2;    // 167,904,256
  if (ws_size < NEED_T2) return;  // loud failure
  bool t3 = ws_size >= NEED_T3;

  char* ws = (char*)d_ws;
  unsigned* meta = (unsigned*)ws;
  unsigned* cnt = meta + 0;
  unsigned* cursor = meta + 8;
  unsigned* offsets = meta + 16;
  int* slot_token = (int*)(ws + 256);
  float* slot_w = (float*)(ws + 65792);
  u16* xbf = (u16*)(ws + XBF_OFF);
  u16* act = (u16*)(ws + ACT_OFF);
  u16* wgT = (u16*)(ws + WGT_OFF);
  u16* wuT = (u16*)(ws + WUT_OFF);
  u16* wdT = (u16*)(ws + WDT_OFF);
  // sel/wt stash inside act (dead once k4 runs)
  char* sel = (char*)act;
  float* wt = (float*)((char*)act + 16384);

  k0_zero<<<2048, 256, 0, stream>>>(out, meta);
  kx_cvt<<<2048, 256, 0, stream>>>(x, xbf);
  if (t3) {
    kt_transpose<<<dim3(IDIM / 64, HDIM / 64, NE), 256, 0, stream>>>(wg, wgT, HDIM, IDIM);
    kt_transpose<<<dim3(IDIM / 64, HDIM / 64, NE), 256, 0, stream>>>(wu, wuT, HDIM, IDIM);
    kt_transpose<<<dim3(HDIM / 64, IDIM / 64, NE), 256, 0, stream>>>(wd, wdT, IDIM, HDIM);
  }
  k1_router<<<T_TOK / 4, 256, 0, stream>>>(x, wgate, logits, sel, wt, cnt);
  k2_prefix<<<1, 64, 0, stream>>>(cnt, offsets, cursor);
  k3_assign<<<T_TOK / 256, 256, 0, stream>>>(sel, wt, offsets, cursor, slot_token, slot_w);
  if (t3) {
    k4_gateup<true><<<dim3(T_TOK / 128, IDIM / 64, NE), 256, 0, stream>>>(
        xbf, wg, wu, wgT, wuT, slot_token, offsets, cnt, act);
    k5_down<true><<<dim3(T_TOK / 128, HDIM / 128, NE), 256, 0, stream>>>(
        act, wd, wdT, slot_token, slot_w, offsets, cnt, out);
  } else {
    k4_gateup<false><<<dim3(T_TOK / 128, IDIM / 64, NE), 256, 0, stream>>>(
        xbf, wg, wu, wgT, wuT, slot_token, offsets, cnt, act);
    k5_down<false><<<dim3(T_TOK / 128, HDIM / 128, NE), 256, 0, stream>>>(
        act, wd, wdT, slot_token, slot_w, offsets, cnt, out);
  }
}

// Round 7
// 954.321 us; speedup vs baseline: 1.2154x; 1.0487x over previous
//
#include <hip/hip_runtime.h>
#include <math.h>

#define T_TOK 8192
#define HDIM 2048
#define IDIM 1024
#define NE 8

typedef __attribute__((ext_vector_type(8))) short short8;
typedef __attribute__((ext_vector_type(4))) float f32x4;
typedef unsigned short u16;

__device__ inline u16 f2bf(float f) {
  unsigned u = __builtin_bit_cast(unsigned, f);
  u += 0x7fffu + ((u >> 16) & 1);  // RNE
  return (u16)(u >> 16);
}

// async global->LDS, 16B/lane. LDS dest = wave-uniform base + lane*16.
__device__ inline void gl_lds(const u16* g, u16* l) {
  __builtin_amdgcn_global_load_lds((const __attribute__((address_space(1))) unsigned int*)g,
                                   (__attribute__((address_space(3))) unsigned int*)l, 16, 0, 0);
}

// bf16 LDS tiles [row][32] (64B rows); chunk swizzle applied on the GLOBAL
// source address (m173 pattern): position p holds global chunk p ^ ((row>>1)&3).
// Frag read of granule g: row*32 + 8*(g ^ ((row>>1)&3)) -> 2-way banks (free).
__device__ inline int rswz(int row, int g) { return row * 32 + 8 * (g ^ ((row >> 1) & 3)); }

// ---------------- K0: zero out region + counters + x->bf16 ----------------
__global__ __launch_bounds__(256) void k0_init(const float* __restrict__ x,
                                               float* __restrict__ out,
                                               u16* __restrict__ xb,
                                               unsigned* __restrict__ meta) {
  size_t i = (size_t)blockIdx.x * blockDim.x + threadIdx.x;
  size_t n4 = (size_t)T_TOK * HDIM / 4;
  float4* o4 = (float4*)out;
  float4 z = make_float4(0.f, 0.f, 0.f, 0.f);
  for (size_t p = i; p < n4; p += (size_t)gridDim.x * blockDim.x) o4[p] = z;
  size_t total = (size_t)T_TOK * HDIM;
  size_t stride = (size_t)gridDim.x * 256 * 8;
  for (size_t p = i * 8; p < total; p += stride) {
    float4 v0 = *(const float4*)(x + p);
    float4 v1 = *(const float4*)(x + p + 4);
    short8 o;
    o[0] = f2bf(v0.x); o[1] = f2bf(v0.y); o[2] = f2bf(v0.z); o[3] = f2bf(v0.w);
    o[4] = f2bf(v1.x); o[5] = f2bf(v1.y); o[6] = f2bf(v1.z); o[7] = f2bf(v1.w);
    *(short8*)(xb + p) = o;
  }
  if (blockIdx.x == 0 && threadIdx.x < 24) meta[threadIdx.x] = 0;
}

// ---------------- KT: weight transpose+cvt: dst[n][k] = bf16(src[k][n]) ----------------
__global__ __launch_bounds__(256) void kt_transpose(const float* __restrict__ src,
                                                    u16* __restrict__ dst, int K, int N) {
  __shared__ u16 t[64][72];
  int e = blockIdx.z;
  src += (size_t)e * K * N;
  dst += (size_t)e * K * N;
  int nb = blockIdx.x * 64, kb = blockIdx.y * 64;
  int tid = threadIdx.x;
  int lk = tid >> 4, ln = (tid & 15) * 4;
#pragma unroll
  for (int p = 0; p < 4; ++p) {
    int k = lk + 16 * p;
    float4 v = *(const float4*)(src + (size_t)(kb + k) * N + nb + ln);
    t[ln + 0][k] = f2bf(v.x);
    t[ln + 1][k] = f2bf(v.y);
    t[ln + 2][k] = f2bf(v.z);
    t[ln + 3][k] = f2bf(v.w);
  }
  __syncthreads();
  int n = tid >> 2, c = tid & 3;
  short8 o0 = *(const short8*)&t[n][c * 16];
  short8 o1 = *(const short8*)&t[n][c * 16 + 8];
  u16* d = dst + (size_t)(nb + n) * K + kb + c * 16;
  *(short8*)d = o0;
  *(short8*)(d + 8) = o1;
}

// ---------------- K1: router ----------------
__global__ __launch_bounds__(256) void k1_router(const float* __restrict__ x,
                                                 const float* __restrict__ wgate,
                                                 float* __restrict__ logits_out,
                                                 char* __restrict__ sel,
                                                 float* __restrict__ wt,
                                                 unsigned* __restrict__ cnt) {
  int wave = threadIdx.x >> 6;
  int lane = threadIdx.x & 63;
  int t = blockIdx.x * 4 + wave;
  float acc[NE];
#pragma unroll
  for (int e = 0; e < NE; ++e) acc[e] = 0.f;
  const float4* xr = (const float4*)(x + (size_t)t * HDIM);
#pragma unroll
  for (int c = 0; c < HDIM / 256; ++c) {
    float4 xv = xr[c * 64 + lane];
    int h = (c * 64 + lane) * 4;
    const float xs[4] = {xv.x, xv.y, xv.z, xv.w};
#pragma unroll
    for (int j = 0; j < 4; ++j) {
      const float* wrow = wgate + (size_t)(h + j) * NE;
#pragma unroll
      for (int e = 0; e < NE; ++e) acc[e] += xs[j] * wrow[e];
    }
  }
#pragma unroll
  for (int e = 0; e < NE; ++e) {
    float v = acc[e];
#pragma unroll
    for (int off = 32; off; off >>= 1) v += __shfl_xor(v, off, 64);
    acc[e] = v;
  }
  if (lane == 0) {
    float m = acc[0];
#pragma unroll
    for (int e = 0; e < NE; ++e) {
      logits_out[(size_t)t * NE + e] = acc[e];
      m = fmaxf(m, acc[e]);
    }
    float p[NE];
#pragma unroll
    for (int e = 0; e < NE; ++e) p[e] = expf(acc[e] - m);
    int b0 = 0;
    float v0 = p[0];
#pragma unroll
    for (int e = 1; e < NE; ++e)
      if (p[e] > v0) { v0 = p[e]; b0 = e; }
    int b1 = -1;
    float v1 = -1.f;
#pragma unroll
    for (int e = 0; e < NE; ++e)
      if (e != b0 && p[e] > v1) { v1 = p[e]; b1 = e; }
    float denom = v0 + v1;
    sel[t * 2 + 0] = (char)b0;
    sel[t * 2 + 1] = (char)b1;
    wt[t * 2 + 0] = v0 / denom;
    wt[t * 2 + 1] = v1 / denom;
    atomicAdd(&cnt[b0], 1u);
    atomicAdd(&cnt[b1], 1u);
  }
}

// ---------------- K2 / K3 ----------------
__global__ void k2_prefix(const unsigned* __restrict__ cnt, unsigned* __restrict__ offsets,
                          unsigned* __restrict__ cursor) {
  if (threadIdx.x == 0) {
    unsigned s = 0;
    for (int e = 0; e < NE; ++e) {
      offsets[e] = s;
      s += cnt[e];
    }
  }
  if (threadIdx.x < NE) cursor[threadIdx.x] = 0;
}

__global__ __launch_bounds__(256) void k3_assign(const char* __restrict__ sel,
                                                 const float* __restrict__ wt,
                                                 const unsigned* __restrict__ offsets,
                                                 unsigned* __restrict__ cursor,
                                                 int* __restrict__ slot_token,
                                                 float* __restrict__ slot_w) {
  int t = blockIdx.x * 256 + threadIdx.x;
#pragma unroll
  for (int k = 0; k < 2; ++k) {
    int e = sel[t * 2 + k];
    unsigned p = atomicAdd(&cursor[e], 1u);
    unsigned s = offsets[e] + p;
    slot_token[s] = t;
    slot_w[s] = wt[t * 2 + k];
  }
}

// ---------------- K4: MFMA gate+up + silu -> bf16 act ----------------
// tile 128m x 64n, 4 waves (64x32 each), BK=32, double-buffered LDS,
// counted-vmcnt pipeline (T3/T4): prefetch stays in flight across barriers.
__global__ __launch_bounds__(256) void k4_gateup(
    const u16* __restrict__ xb, const u16* __restrict__ wgT, const u16* __restrict__ wuT,
    const int* __restrict__ slot_token, const unsigned* __restrict__ offsets,
    const unsigned* __restrict__ cnt, u16* __restrict__ act) {
  int e = blockIdx.z;
  unsigned n = cnt[e];
  unsigned row0 = blockIdx.x * 128;
  if (row0 >= n) return;
  unsigned base = offsets[e];
  int col0 = blockIdx.y * 64;

  __shared__ __align__(16) u16 As[2][128 * 32];
  __shared__ __align__(16) u16 Bs[2][2][64 * 32];

  int tid = threadIdx.x;
  int w = tid >> 6, l = tid & 63;
  int wr = w >> 1, wc = w & 1;
  int lr = l & 15, g = l >> 4;

  // A: 2 gl_lds/wave (16 rows each)
  const u16* asrc[2];
  int adst[2];
#pragma unroll
  for (int i = 0; i < 2; ++i) {
    int r = 32 * w + 16 * i + (l >> 2);
    unsigned grow = row0 + (unsigned)r;
    unsigned slot = base + (grow < n ? grow : 0);
    int chunk = (l & 3) ^ ((r >> 1) & 3);
    asrc[i] = xb + (size_t)slot_token[slot] * HDIM + 8 * chunk;
    adst[i] = (32 * w + 16 * i) * 32;
  }
  // B: 1 gl_lds/wave per matrix (16 n-rows each)
  const u16* bsrcT[2];
  int bdstT = 16 * w * 32;
  {
    int nn = 16 * w + (l >> 2);
    int chunk = (l & 3) ^ ((nn >> 1) & 3);
    bsrcT[0] = wgT + (size_t)e * HDIM * IDIM + (size_t)(col0 + nn) * HDIM + 8 * chunk;
    bsrcT[1] = wuT + (size_t)e * HDIM * IDIM + (size_t)(col0 + nn) * HDIM + 8 * chunk;
  }

  int afo[4], bfo[2];
#pragma unroll
  for (int mf = 0; mf < 4; ++mf) afo[mf] = rswz(wr * 64 + mf * 16 + lr, g);
#pragma unroll
  for (int nf = 0; nf < 2; ++nf) bfo[nf] = rswz(wc * 32 + nf * 16 + lr, g);

  f32x4 accg[4][2] = {};
  f32x4 accu[4][2] = {};

#define K4_STAGE(k0, buf)                          \
  do {                                             \
    gl_lds(asrc[0] + (k0), &As[buf][adst[0]]);     \
    gl_lds(asrc[1] + (k0), &As[buf][adst[1]]);     \
    gl_lds(bsrcT[0] + (k0), &Bs[buf][0][bdstT]);   \
    gl_lds(bsrcT[1] + (k0), &Bs[buf][1][bdstT]);   \
  } while (0)

  K4_STAGE(0, 0);  // 4 loads in flight

  const int NK = HDIM / 32;
  for (int kt = 0; kt < NK; ++kt) {
    int c = kt & 1;
    if (kt + 1 < NK) {
      K4_STAGE((kt + 1) * 32, c ^ 1);  // 4 newest loads -> next buffer
      asm volatile("s_waitcnt vmcnt(4)" ::: "memory");  // tile-t loads landed
    } else {
      asm volatile("s_waitcnt vmcnt(0)" ::: "memory");
    }
    __builtin_amdgcn_s_barrier();  // buf c ready for everyone

    short8 af[4];
#pragma unroll
    for (int mf = 0; mf < 4; ++mf) af[mf] = *(const short8*)&As[c][afo[mf]];
#pragma unroll
    for (int nf = 0; nf < 2; ++nf) {
      short8 bgf = *(const short8*)&Bs[c][0][bfo[nf]];
      short8 buf = *(const short8*)&Bs[c][1][bfo[nf]];
#pragma unroll
      for (int mf = 0; mf < 4; ++mf) {
        accg[mf][nf] = __builtin_amdgcn_mfma_f32_16x16x32_bf16(af[mf], bgf, accg[mf][nf], 0, 0, 0);
        accu[mf][nf] = __builtin_amdgcn_mfma_f32_16x16x32_bf16(af[mf], buf, accu[mf][nf], 0, 0, 0);
      }
    }
    __builtin_amdgcn_s_barrier();  // all reads of buf c done -> safe to overwrite
  }
#undef K4_STAGE

  unsigned rows_left = n - row0;
#pragma unroll
  for (int mf = 0; mf < 4; ++mf)
#pragma unroll
    for (int nf = 0; nf < 2; ++nf)
#pragma unroll
      for (int j = 0; j < 4; ++j) {
        int rin = wr * 64 + mf * 16 + 4 * g + j;
        if ((unsigned)rin < rows_left) {
          size_t s = base + row0 + rin;
          int col = col0 + wc * 32 + nf * 16 + lr;
          float gg = accg[mf][nf][j];
          float uu = accu[mf][nf][j];
          float v = (gg / (1.f + expf(-gg))) * uu;
          act[s * IDIM + col] = f2bf(v);
        }
      }
}

// ---------------- K5: MFMA down + weighted atomic combine ----------------
// tile 128m x 128n, 4 waves (64x64 each), BK=32, counted-vmcnt pipeline.
__global__ __launch_bounds__(256) void k5_down(
    const u16* __restrict__ act, const u16* __restrict__ wdT,
    const int* __restrict__ slot_token, const float* __restrict__ slot_w,
    const unsigned* __restrict__ offsets, const unsigned* __restrict__ cnt,
    float* __restrict__ out) {
  int e = blockIdx.z;
  unsigned n = cnt[e];
  unsigned row0 = blockIdx.x * 128;
  if (row0 >= n) return;
  unsigned base = offsets[e];
  int col0 = blockIdx.y * 128;

  __shared__ __align__(16) u16 As[2][128 * 32];
  __shared__ __align__(16) u16 Bs[2][128 * 32];

  int tid = threadIdx.x;
  int w = tid >> 6, l = tid & 63;
  int wr = w >> 1, wc = w & 1;
  int lr = l & 15, g = l >> 4;

  const u16* asrc[2];
  int adst[2];
#pragma unroll
  for (int i = 0; i < 2; ++i) {
    int r = 32 * w + 16 * i + (l >> 2);
    unsigned grow = row0 + (unsigned)r;
    unsigned slot = base + (grow < n ? grow : 0);
    int chunk = (l & 3) ^ ((r >> 1) & 3);
    asrc[i] = act + (size_t)slot * IDIM + 8 * chunk;
    adst[i] = (32 * w + 16 * i) * 32;
  }
  const u16* bsrcT[2];
  int bdstT[2];
#pragma unroll
  for (int i = 0; i < 2; ++i) {
    int nn = 32 * w + 16 * i + (l >> 2);
    int chunk = (l & 3) ^ ((nn >> 1) & 3);
    bsrcT[i] = wdT + (size_t)e * IDIM * HDIM + (size_t)(col0 + nn) * IDIM + 8 * chunk;
    bdstT[i] = (32 * w + 16 * i) * 32;
  }

  int afo[4], bfo[4];
#pragma unroll
  for (int mf = 0; mf < 4; ++mf) afo[mf] = rswz(wr * 64 + mf * 16 + lr, g);
#pragma unroll
  for (int nf = 0; nf < 4; ++nf) bfo[nf] = rswz(wc * 64 + nf * 16 + lr, g);

  f32x4 acc[4][4] = {};

#define K5_STAGE(k0, buf)                           \
  do {                                              \
    gl_lds(asrc[0] + (k0), &As[buf][adst[0]]);      \
    gl_lds(asrc[1] + (k0), &As[buf][adst[1]]);      \
    gl_lds(bsrcT[0] + (k0), &Bs[buf][bdstT[0]]);    \
    gl_lds(bsrcT[1] + (k0), &Bs[buf][bdstT[1]]);    \
  } while (0)

  K5_STAGE(0, 0);

  const int NK = IDIM / 32;
  for (int kt = 0; kt < NK; ++kt) {
    int c = kt & 1;
    if (kt + 1 < NK) {
      K5_STAGE((kt + 1) * 32, c ^ 1);
      asm volatile("s_waitcnt vmcnt(4)" ::: "memory");
    } else {
      asm volatile("s_waitcnt vmcnt(0)" ::: "memory");
    }
    __builtin_amdgcn_s_barrier();

    short8 af[4];
#pragma unroll
    for (int mf = 0; mf < 4; ++mf) af[mf] = *(const short8*)&As[c][afo[mf]];
#pragma unroll
    for (int nf = 0; nf < 4; ++nf) {
      short8 bd = *(const short8*)&Bs[c][bfo[nf]];
#pragma unroll
      for (int mf = 0; mf < 4; ++mf)
        acc[mf][nf] = __builtin_amdgcn_mfma_f32_16x16x32_bf16(af[mf], bd, acc[mf][nf], 0, 0, 0);
    }
    __builtin_amdgcn_s_barrier();
  }
#undef K5_STAGE

  unsigned rows_left = n - row0;
#pragma unroll
  for (int mf = 0; mf < 4; ++mf)
#pragma unroll
    for (int j = 0; j < 4; ++j) {
      int rin = wr * 64 + mf * 16 + 4 * g + j;
      if ((unsigned)rin < rows_left) {
        size_t s = base + row0 + rin;
        int token = slot_token[s];
        float wgt = slot_w[s];
        float* orow = out + (size_t)token * HDIM + col0 + wc * 64 + lr;
#pragma unroll
        for (int nf = 0; nf < 4; ++nf) atomicAdd(&orow[nf * 16], wgt * acc[mf][nf][j]);
      }
    }
}

extern "C" void kernel_launch(void* const* d_in, const int* in_sizes, int n_in,
                              void* d_out, int out_size, void* d_ws, size_t ws_size,
                              hipStream_t stream) {
  const float* x = (const float*)d_in[0];
  const float* wgate = (const float*)d_in[1];
  const float* wg = (const float*)d_in[2];
  const float* wu = (const float*)d_in[3];
  const float* wd = (const float*)d_in[4];
  float* out = (float*)d_out;
  float* logits = out + (size_t)T_TOK * HDIM;

  const size_t XBF_OFF = 132096;
  const size_t ACT_OFF = XBF_OFF + (size_t)T_TOK * HDIM * 2;
  const size_t WGT_OFF = ACT_OFF + (size_t)2 * T_TOK * IDIM * 2;
  const size_t WUT_OFF = WGT_OFF + (size_t)NE * HDIM * IDIM * 2;
  const size_t WDT_OFF = WUT_OFF + (size_t)NE * HDIM * IDIM * 2;
  const size_t NEED_T3 = WDT_OFF + (size_t)NE * IDIM * HDIM * 2;  // 167,904,256 (proven in R5)
  if (ws_size < NEED_T3) return;  // loud failure

  char* ws = (char*)d_ws;
  unsigned* meta = (unsigned*)ws;
  unsigned* cnt = meta + 0;
  unsigned* cursor = meta + 8;
  unsigned* offsets = meta + 16;
  int* slot_token = (int*)(ws + 256);
  float* slot_w = (float*)(ws + 65792);
  u16* xbf = (u16*)(ws + XBF_OFF);
  u16* act = (u16*)(ws + ACT_OFF);
  u16* wgT = (u16*)(ws + WGT_OFF);
  u16* wuT = (u16*)(ws + WUT_OFF);
  u16* wdT = (u16*)(ws + WDT_OFF);
  char* sel = (char*)act;                       // dead before k4 writes act
  float* wt = (float*)((char*)act + 16384);

  k0_init<<<2048, 256, 0, stream>>>(x, out, xbf, meta);
  kt_transpose<<<dim3(IDIM / 64, HDIM / 64, NE), 256, 0, stream>>>(wg, wgT, HDIM, IDIM);
  kt_transpose<<<dim3(IDIM / 64, HDIM / 64, NE), 256, 0, stream>>>(wu, wuT, HDIM, IDIM);
  kt_transpose<<<dim3(HDIM / 64, IDIM / 64, NE), 256, 0, stream>>>(wd, wdT, IDIM, HDIM);
  k1_router<<<T_TOK / 4, 256, 0, stream>>>(x, wgate, logits, sel, wt, cnt);
  k2_prefix<<<1, 64, 0, stream>>>(cnt, offsets, cursor);
  k3_assign<<<T_TOK / 256, 256, 0, stream>>>(sel, wt, offsets, cursor, slot_token, slot_w);
  k4_gateup<<<dim3(T_TOK / 128, IDIM / 64, NE), 256, 0, stream>>>(xbf, wgT, wuT, slot_token,
                                                                  offsets, cnt, act);
  k5_down<<<dim3(T_TOK / 128, HDIM / 128, NE), 256, 0, stream>>>(act, wdT, slot_token, slot_w,
                                                                 offsets, cnt, out);
}

// Round 8
// 793.169 us; speedup vs baseline: 1.4624x; 1.2032x over previous
//
#include <hip/hip_runtime.h>
#include <math.h>

#define T_TOK 8192
#define HDIM 2048
#define IDIM 1024
#define NE 8

typedef __attribute__((ext_vector_type(8))) short short8;
typedef __attribute__((ext_vector_type(4))) float f32x4;
typedef unsigned short u16;

__device__ inline u16 f2bf(float f) {
  unsigned u = __builtin_bit_cast(unsigned, f);
  u += 0x7fffu + ((u >> 16) & 1);  // RNE
  return (u16)(u >> 16);
}

// async global->LDS, 16B/lane. LDS dest = wave-uniform base + lane*16.
__device__ inline void gl_lds(const u16* g, u16* l) {
  __builtin_amdgcn_global_load_lds((const __attribute__((address_space(1))) unsigned int*)g,
                                   (__attribute__((address_space(3))) unsigned int*)l, 16, 0, 0);
}

// bf16 LDS tiles [row][32] (64B rows); chunk swizzle applied on the GLOBAL
// source address (m173 pattern): position p holds global chunk p ^ ((row>>1)&3).
// Frag read of granule g: row*32 + 8*(g ^ ((row>>1)&3)) -> 2-way banks (free).
__device__ inline int rswz(int row, int g) { return row * 32 + 8 * (g ^ ((row >> 1) & 3)); }

// ---------------- K0: zero out region + counters + x->bf16 ----------------
__global__ __launch_bounds__(256) void k0_init(const float* __restrict__ x,
                                               float* __restrict__ out,
                                               u16* __restrict__ xb,
                                               unsigned* __restrict__ meta) {
  size_t i = (size_t)blockIdx.x * blockDim.x + threadIdx.x;
  size_t n4 = (size_t)T_TOK * HDIM / 4;
  float4* o4 = (float4*)out;
  float4 z = make_float4(0.f, 0.f, 0.f, 0.f);
  for (size_t p = i; p < n4; p += (size_t)gridDim.x * blockDim.x) o4[p] = z;
  size_t total = (size_t)T_TOK * HDIM;
  size_t stride = (size_t)gridDim.x * 256 * 8;
  for (size_t p = i * 8; p < total; p += stride) {
    float4 v0 = *(const float4*)(x + p);
    float4 v1 = *(const float4*)(x + p + 4);
    short8 o;
    o[0] = f2bf(v0.x); o[1] = f2bf(v0.y); o[2] = f2bf(v0.z); o[3] = f2bf(v0.w);
    o[4] = f2bf(v1.x); o[5] = f2bf(v1.y); o[6] = f2bf(v1.z); o[7] = f2bf(v1.w);
    *(short8*)(xb + p) = o;
  }
  if (blockIdx.x == 0 && threadIdx.x < 24) meta[threadIdx.x] = 0;
}

// ---------------- KT: weight transpose+cvt: dst[n][k] = bf16(src[k][n]) ----------------
__global__ __launch_bounds__(256) void kt_transpose(const float* __restrict__ src,
                                                    u16* __restrict__ dst, int K, int N) {
  __shared__ u16 t[64][72];
  int e = blockIdx.z;
  src += (size_t)e * K * N;
  dst += (size_t)e * K * N;
  int nb = blockIdx.x * 64, kb = blockIdx.y * 64;
  int tid = threadIdx.x;
  int lk = tid >> 4, ln = (tid & 15) * 4;
#pragma unroll
  for (int p = 0; p < 4; ++p) {
    int k = lk + 16 * p;
    float4 v = *(const float4*)(src + (size_t)(kb + k) * N + nb + ln);
    t[ln + 0][k] = f2bf(v.x);
    t[ln + 1][k] = f2bf(v.y);
    t[ln + 2][k] = f2bf(v.z);
    t[ln + 3][k] = f2bf(v.w);
  }
  __syncthreads();
  int n = tid >> 2, c = tid & 3;
  short8 o0 = *(const short8*)&t[n][c * 16];
  short8 o1 = *(const short8*)&t[n][c * 16 + 8];
  u16* d = dst + (size_t)(nb + n) * K + kb + c * 16;
  *(short8*)d = o0;
  *(short8*)(d + 8) = o1;
}

// ---------------- K1: router ----------------
__global__ __launch_bounds__(256) void k1_router(const float* __restrict__ x,
                                                 const float* __restrict__ wgate,
                                                 float* __restrict__ logits_out,
                                                 char* __restrict__ sel,
                                                 float* __restrict__ wt,
                                                 unsigned* __restrict__ cnt) {
  int wave = threadIdx.x >> 6;
  int lane = threadIdx.x & 63;
  int t = blockIdx.x * 4 + wave;
  float acc[NE];
#pragma unroll
  for (int e = 0; e < NE; ++e) acc[e] = 0.f;
  const float4* xr = (const float4*)(x + (size_t)t * HDIM);
#pragma unroll
  for (int c = 0; c < HDIM / 256; ++c) {
    float4 xv = xr[c * 64 + lane];
    int h = (c * 64 + lane) * 4;
    const float xs[4] = {xv.x, xv.y, xv.z, xv.w};
#pragma unroll
    for (int j = 0; j < 4; ++j) {
      const float* wrow = wgate + (size_t)(h + j) * NE;
#pragma unroll
      for (int e = 0; e < NE; ++e) acc[e] += xs[j] * wrow[e];
    }
  }
#pragma unroll
  for (int e = 0; e < NE; ++e) {
    float v = acc[e];
#pragma unroll
    for (int off = 32; off; off >>= 1) v += __shfl_xor(v, off, 64);
    acc[e] = v;
  }
  if (lane == 0) {
    float m = acc[0];
#pragma unroll
    for (int e = 0; e < NE; ++e) {
      logits_out[(size_t)t * NE + e] = acc[e];
      m = fmaxf(m, acc[e]);
    }
    float p[NE];
#pragma unroll
    for (int e = 0; e < NE; ++e) p[e] = expf(acc[e] - m);
    int b0 = 0;
    float v0 = p[0];
#pragma unroll
    for (int e = 1; e < NE; ++e)
      if (p[e] > v0) { v0 = p[e]; b0 = e; }
    int b1 = -1;
    float v1 = -1.f;
#pragma unroll
    for (int e = 0; e < NE; ++e)
      if (e != b0 && p[e] > v1) { v1 = p[e]; b1 = e; }
    float denom = v0 + v1;
    sel[t * 2 + 0] = (char)b0;
    sel[t * 2 + 1] = (char)b1;
    wt[t * 2 + 0] = v0 / denom;
    wt[t * 2 + 1] = v1 / denom;
    atomicAdd(&cnt[b0], 1u);
    atomicAdd(&cnt[b1], 1u);
  }
}

// ---------------- K2 / K3 ----------------
__global__ void k2_prefix(const unsigned* __restrict__ cnt, unsigned* __restrict__ offsets,
                          unsigned* __restrict__ cursor) {
  if (threadIdx.x == 0) {
    unsigned s = 0;
    for (int e = 0; e < NE; ++e) {
      offsets[e] = s;
      s += cnt[e];
    }
  }
  if (threadIdx.x < NE) cursor[threadIdx.x] = 0;
}

__global__ __launch_bounds__(256) void k3_assign(const char* __restrict__ sel,
                                                 const float* __restrict__ wt,
                                                 const unsigned* __restrict__ offsets,
                                                 unsigned* __restrict__ cursor,
                                                 int* __restrict__ slot_token,
                                                 float* __restrict__ slot_w) {
  int t = blockIdx.x * 256 + threadIdx.x;
#pragma unroll
  for (int k = 0; k < 2; ++k) {
    int e = sel[t * 2 + k];
    unsigned p = atomicAdd(&cursor[e], 1u);
    unsigned s = offsets[e] + p;
    slot_token[s] = t;
    slot_w[s] = wt[t * 2 + k];
  }
}

// Bijective XCD swizzle for 64x16x8 = 8192-block grids (8 XCDs, 1024/XCD):
// hw bid -> logical swz; each XCD gets a contiguous logical chunk, so the 64
// row-blocks sharing one B-slice co-reside on one XCD's L2.
__device__ inline void xcd_decomp(int& bx, int& by, int& be) {
  unsigned bid = blockIdx.x + 64u * (blockIdx.y + 16u * blockIdx.z);
  unsigned swz = (bid & 7u) * 1024u + (bid >> 3);
  bx = swz & 63u;
  unsigned rem = swz >> 6;
  by = rem & 15u;
  be = rem >> 4;
}

// ---------------- K4: MFMA gate+up + silu -> bf16 act ----------------
// tile 128m x 64n, 4 waves (64x32 each), BK=32, ring-3 LDS, depth-2 prefetch:
// 12 loads in flight, vmcnt(8) -> current tile landed, 2 newer stay in flight.
__global__ __launch_bounds__(256) void k4_gateup(
    const u16* __restrict__ xb, const u16* __restrict__ wgT, const u16* __restrict__ wuT,
    const int* __restrict__ slot_token, const unsigned* __restrict__ offsets,
    const unsigned* __restrict__ cnt, u16* __restrict__ act) {
  int bx, by, e;
  xcd_decomp(bx, by, e);
  unsigned n = cnt[e];
  unsigned row0 = (unsigned)bx * 128;
  if (row0 >= n) return;
  unsigned base = offsets[e];
  int col0 = by * 64;

  __shared__ __align__(16) u16 As[3][128 * 32];       // 24 KB
  __shared__ __align__(16) u16 Bs[3][2][64 * 32];     // 24 KB

  int tid = threadIdx.x;
  int w = tid >> 6, l = tid & 63;
  int wr = w >> 1, wc = w & 1;
  int lr = l & 15, g = l >> 4;

  // A: 2 gl_lds/wave (16 rows each)
  const u16* asrc[2];
  int adst[2];
#pragma unroll
  for (int i = 0; i < 2; ++i) {
    int r = 32 * w + 16 * i + (l >> 2);
    unsigned grow = row0 + (unsigned)r;
    unsigned slot = base + (grow < n ? grow : 0);
    int chunk = (l & 3) ^ ((r >> 1) & 3);
    asrc[i] = xb + (size_t)slot_token[slot] * HDIM + 8 * chunk;
    adst[i] = (32 * w + 16 * i) * 32;
  }
  // B: 1 gl_lds/wave per matrix (16 n-rows each)
  const u16* bsrcT[2];
  int bdstT = 16 * w * 32;
  {
    int nn = 16 * w + (l >> 2);
    int chunk = (l & 3) ^ ((nn >> 1) & 3);
    bsrcT[0] = wgT + (size_t)e * HDIM * IDIM + (size_t)(col0 + nn) * HDIM + 8 * chunk;
    bsrcT[1] = wuT + (size_t)e * HDIM * IDIM + (size_t)(col0 + nn) * HDIM + 8 * chunk;
  }

  int afo[4], bfo[2];
#pragma unroll
  for (int mf = 0; mf < 4; ++mf) afo[mf] = rswz(wr * 64 + mf * 16 + lr, g);
#pragma unroll
  for (int nf = 0; nf < 2; ++nf) bfo[nf] = rswz(wc * 32 + nf * 16 + lr, g);

  f32x4 accg[4][2] = {};
  f32x4 accu[4][2] = {};

#define K4_STAGE(k0, buf)                          \
  do {                                             \
    gl_lds(asrc[0] + (k0), &As[buf][adst[0]]);     \
    gl_lds(asrc[1] + (k0), &As[buf][adst[1]]);     \
    gl_lds(bsrcT[0] + (k0), &Bs[buf][0][bdstT]);   \
    gl_lds(bsrcT[1] + (k0), &Bs[buf][1][bdstT]);   \
  } while (0)

  K4_STAGE(0, 0);
  K4_STAGE(32, 1);  // 8 loads in flight

  const int NK = HDIM / 32;
  int c = 0, sb = 2;  // compute buffer, stage buffer
  for (int kt = 0; kt < NK; ++kt) {
    if (kt + 2 < NK) {
      K4_STAGE((kt + 2) * 32, sb);                      // 12 in flight
      asm volatile("s_waitcnt vmcnt(8)" ::: "memory");  // tile kt landed
    } else if (kt + 1 < NK) {
      asm volatile("s_waitcnt vmcnt(4)" ::: "memory");
    } else {
      asm volatile("s_waitcnt vmcnt(0)" ::: "memory");
    }
    __builtin_amdgcn_s_barrier();  // buf c fully written for all waves

    short8 af[4];
#pragma unroll
    for (int mf = 0; mf < 4; ++mf) af[mf] = *(const short8*)&As[c][afo[mf]];
#pragma unroll
    for (int nf = 0; nf < 2; ++nf) {
      short8 bgf = *(const short8*)&Bs[c][0][bfo[nf]];
      short8 buf = *(const short8*)&Bs[c][1][bfo[nf]];
#pragma unroll
      for (int mf = 0; mf < 4; ++mf) {
        accg[mf][nf] = __builtin_amdgcn_mfma_f32_16x16x32_bf16(af[mf], bgf, accg[mf][nf], 0, 0, 0);
        accu[mf][nf] = __builtin_amdgcn_mfma_f32_16x16x32_bf16(af[mf], buf, accu[mf][nf], 0, 0, 0);
      }
    }
    __builtin_amdgcn_s_barrier();  // reads of buf c done -> iter kt+1 may stage into it
    c = (c == 2) ? 0 : c + 1;
    sb = (sb == 2) ? 0 : sb + 1;
  }
#undef K4_STAGE

  unsigned rows_left = n - row0;
#pragma unroll
  for (int mf = 0; mf < 4; ++mf)
#pragma unroll
    for (int nf = 0; nf < 2; ++nf)
#pragma unroll
      for (int j = 0; j < 4; ++j) {
        int rin = wr * 64 + mf * 16 + 4 * g + j;
        if ((unsigned)rin < rows_left) {
          size_t s = base + row0 + rin;
          int col = col0 + wc * 32 + nf * 16 + lr;
          float gg = accg[mf][nf][j];
          float uu = accu[mf][nf][j];
          float v = (gg / (1.f + expf(-gg))) * uu;
          act[s * IDIM + col] = f2bf(v);
        }
      }
}

// ---------------- K5: MFMA down + weighted atomic combine ----------------
// tile 128m x 128n, 4 waves (64x64 each), BK=32, ring-3 LDS, depth-2 prefetch.
__global__ __launch_bounds__(256) void k5_down(
    const u16* __restrict__ act, const u16* __restrict__ wdT,
    const int* __restrict__ slot_token, const float* __restrict__ slot_w,
    const unsigned* __restrict__ offsets, const unsigned* __restrict__ cnt,
    float* __restrict__ out) {
  int bx, by, e;
  xcd_decomp(bx, by, e);
  unsigned n = cnt[e];
  unsigned row0 = (unsigned)bx * 128;
  if (row0 >= n) return;
  unsigned base = offsets[e];
  int col0 = by * 128;

  __shared__ __align__(16) u16 As[3][128 * 32];   // 24 KB
  __shared__ __align__(16) u16 Bs[3][128 * 32];   // 24 KB

  int tid = threadIdx.x;
  int w = tid >> 6, l = tid & 63;
  int wr = w >> 1, wc = w & 1;
  int lr = l & 15, g = l >> 4;

  const u16* asrc[2];
  int adst[2];
#pragma unroll
  for (int i = 0; i < 2; ++i) {
    int r = 32 * w + 16 * i + (l >> 2);
    unsigned grow = row0 + (unsigned)r;
    unsigned slot = base + (grow < n ? grow : 0);
    int chunk = (l & 3) ^ ((r >> 1) & 3);
    asrc[i] = act + (size_t)slot * IDIM + 8 * chunk;
    adst[i] = (32 * w + 16 * i) * 32;
  }
  const u16* bsrcT[2];
  int bdstT[2];
#pragma unroll
  for (int i = 0; i < 2; ++i) {
    int nn = 32 * w + 16 * i + (l >> 2);
    int chunk = (l & 3) ^ ((nn >> 1) & 3);
    bsrcT[i] = wdT + (size_t)e * IDIM * HDIM + (size_t)(col0 + nn) * IDIM + 8 * chunk;
    bdstT[i] = (32 * w + 16 * i) * 32;
  }

  int afo[4], bfo[4];
#pragma unroll
  for (int mf = 0; mf < 4; ++mf) afo[mf] = rswz(wr * 64 + mf * 16 + lr, g);
#pragma unroll
  for (int nf = 0; nf < 4; ++nf) bfo[nf] = rswz(wc * 64 + nf * 16 + lr, g);

  f32x4 acc[4][4] = {};

#define K5_STAGE(k0, buf)                           \
  do {                                              \
    gl_lds(asrc[0] + (k0), &As[buf][adst[0]]);      \
    gl_lds(asrc[1] + (k0), &As[buf][adst[1]]);      \
    gl_lds(bsrcT[0] + (k0), &Bs[buf][bdstT[0]]);    \
    gl_lds(bsrcT[1] + (k0), &Bs[buf][bdstT[1]]);    \
  } while (0)

  K5_STAGE(0, 0);
  K5_STAGE(32, 1);

  const int NK = IDIM / 32;
  int c = 0, sb = 2;
  for (int kt = 0; kt < NK; ++kt) {
    if (kt + 2 < NK) {
      K5_STAGE((kt + 2) * 32, sb);
      asm volatile("s_waitcnt vmcnt(8)" ::: "memory");
    } else if (kt + 1 < NK) {
      asm volatile("s_waitcnt vmcnt(4)" ::: "memory");
    } else {
      asm volatile("s_waitcnt vmcnt(0)" ::: "memory");
    }
    __builtin_amdgcn_s_barrier();

    short8 af[4];
#pragma unroll
    for (int mf = 0; mf < 4; ++mf) af[mf] = *(const short8*)&As[c][afo[mf]];
#pragma unroll
    for (int nf = 0; nf < 4; ++nf) {
      short8 bd = *(const short8*)&Bs[c][bfo[nf]];
#pragma unroll
      for (int mf = 0; mf < 4; ++mf)
        acc[mf][nf] = __builtin_amdgcn_mfma_f32_16x16x32_bf16(af[mf], bd, acc[mf][nf], 0, 0, 0);
    }
    __builtin_amdgcn_s_barrier();
    c = (c == 2) ? 0 : c + 1;
    sb = (sb == 2) ? 0 : sb + 1;
  }
#undef K5_STAGE

  unsigned rows_left = n - row0;
#pragma unroll
  for (int mf = 0; mf < 4; ++mf)
#pragma unroll
    for (int j = 0; j < 4; ++j) {
      int rin = wr * 64 + mf * 16 + 4 * g + j;
      if ((unsigned)rin < rows_left) {
        size_t s = base + row0 + rin;
        int token = slot_token[s];
        float wgt = slot_w[s];
        float* orow = out + (size_t)token * HDIM + col0 + wc * 64 + lr;
#pragma unroll
        for (int nf = 0; nf < 4; ++nf) atomicAdd(&orow[nf * 16], wgt * acc[mf][nf][j]);
      }
    }
}

extern "C" void kernel_launch(void* const* d_in, const int* in_sizes, int n_in,
                              void* d_out, int out_size, void* d_ws, size_t ws_size,
                              hipStream_t stream) {
  const float* x = (const float*)d_in[0];
  const float* wgate = (const float*)d_in[1];
  const float* wg = (const float*)d_in[2];
  const float* wu = (const float*)d_in[3];
  const float* wd = (const float*)d_in[4];
  float* out = (float*)d_out;
  float* logits = out + (size_t)T_TOK * HDIM;

  const size_t XBF_OFF = 132096;
  const size_t ACT_OFF = XBF_OFF + (size_t)T_TOK * HDIM * 2;
  const size_t WGT_OFF = ACT_OFF + (size_t)2 * T_TOK * IDIM * 2;
  const size_t WUT_OFF = WGT_OFF + (size_t)NE * HDIM * IDIM * 2;
  const size_t WDT_OFF = WUT_OFF + (size_t)NE * HDIM * IDIM * 2;
  const size_t NEED_T3 = WDT_OFF + (size_t)NE * IDIM * HDIM * 2;  // 167,904,256 (proven in R5)
  if (ws_size < NEED_T3) return;  // loud failure

  char* ws = (char*)d_ws;
  unsigned* meta = (unsigned*)ws;
  unsigned* cnt = meta + 0;
  unsigned* cursor = meta + 8;
  unsigned* offsets = meta + 16;
  int* slot_token = (int*)(ws + 256);
  float* slot_w = (float*)(ws + 65792);
  u16* xbf = (u16*)(ws + XBF_OFF);
  u16* act = (u16*)(ws + ACT_OFF);
  u16* wgT = (u16*)(ws + WGT_OFF);
  u16* wuT = (u16*)(ws + WUT_OFF);
  u16* wdT = (u16*)(ws + WDT_OFF);
  char* sel = (char*)act;                       // dead before k4 writes act
  float* wt = (float*)((char*)act + 16384);

  k0_init<<<2048, 256, 0, stream>>>(x, out, xbf, meta);
  kt_transpose<<<dim3(IDIM / 64, HDIM / 64, NE), 256, 0, stream>>>(wg, wgT, HDIM, IDIM);
  kt_transpose<<<dim3(IDIM / 64, HDIM / 64, NE), 256, 0, stream>>>(wu, wuT, HDIM, IDIM);
  kt_transpose<<<dim3(HDIM / 64, IDIM / 64, NE), 256, 0, stream>>>(wd, wdT, IDIM, HDIM);
  k1_router<<<T_TOK / 4, 256, 0, stream>>>(x, wgate, logits, sel, wt, cnt);
  k2_prefix<<<1, 64, 0, stream>>>(cnt, offsets, cursor);
  k3_assign<<<T_TOK / 256, 256, 0, stream>>>(sel, wt, offsets, cursor, slot_token, slot_w);
  k4_gateup<<<dim3(T_TOK / 128, IDIM / 64, NE), 256, 0, stream>>>(xbf, wgT, wuT, slot_token,
                                                                  offsets, cnt, act);
  k5_down<<<dim3(T_TOK / 128, HDIM / 128, NE), 256, 0, stream>>>(act, wdT, slot_token, slot_w,
                                                                 offsets, cnt, out);
}

// Round 9
// 683.786 us; speedup vs baseline: 1.6963x; 1.1600x over previous
//
#include <hip/hip_runtime.h>
#include <math.h>

#define T_TOK 8192
#define HDIM 2048
#define IDIM 1024
#define NE 8

typedef __attribute__((ext_vector_type(8))) short short8;
typedef __attribute__((ext_vector_type(4))) float f32x4;
typedef unsigned short u16;

__device__ inline u16 f2bf(float f) {
  unsigned u = __builtin_bit_cast(unsigned, f);
  u += 0x7fffu + ((u >> 16) & 1);  // RNE
  return (u16)(u >> 16);
}
__device__ inline float bf2f(u16 u) {
  unsigned v = (unsigned)u << 16;
  return __builtin_bit_cast(float, v);
}

// async global->LDS, 16B/lane. LDS dest = wave-uniform base + lane*16.
__device__ inline void gl_lds(const u16* g, u16* l) {
  __builtin_amdgcn_global_load_lds((const __attribute__((address_space(1))) unsigned int*)g,
                                   (__attribute__((address_space(3))) unsigned int*)l, 16, 0, 0);
}

// bf16 LDS tiles [row][32] (64B rows); chunk swizzle applied on the GLOBAL
// source address (m173): position p holds global chunk p ^ ((row>>1)&3).
// Frag read of granule g: row*32 + 8*(g ^ ((row>>1)&3)) -> 2-way banks (free).
__device__ inline int rswz(int row, int g) { return row * 32 + 8 * (g ^ ((row >> 1) & 3)); }

// ---------- ws layout ----------
// 0       meta: cnt[8] cursor[8] offsets[8] (u32)
// 256     slot_token u16[2T]  (32 KB)
// 33024   slot_w    f32[2T]   (64 KB)
// 98560   tok2slot  u16[2T]   (32 KB)   -> ends 131328
// 132096  xbf  bf16[T*H]      (33.5 MB)
// ACT     act  bf16[2T*I]     (33.5 MB)  (sel/wt stashed here pre-k4)
// WGT     wgT / wuT           (67 MB)    -> y bf16[2T*H] after k4 (exact fit)
// WDT     wdT                 (33.5 MB)  total 167,904,256 (proven R5)

// ---------------- K0: x->bf16 + zero counters ----------------
__global__ __launch_bounds__(256) void k0_init(const float* __restrict__ x,
                                               u16* __restrict__ xb,
                                               unsigned* __restrict__ meta) {
  size_t i = (size_t)blockIdx.x * blockDim.x + threadIdx.x;
  size_t total = (size_t)T_TOK * HDIM;
  size_t stride = (size_t)gridDim.x * 256 * 8;
  for (size_t p = i * 8; p < total; p += stride) {
    float4 v0 = *(const float4*)(x + p);
    float4 v1 = *(const float4*)(x + p + 4);
    short8 o;
    o[0] = f2bf(v0.x); o[1] = f2bf(v0.y); o[2] = f2bf(v0.z); o[3] = f2bf(v0.w);
    o[4] = f2bf(v1.x); o[5] = f2bf(v1.y); o[6] = f2bf(v1.z); o[7] = f2bf(v1.w);
    *(short8*)(xb + p) = o;
  }
  if (blockIdx.x == 0 && threadIdx.x < 24) meta[threadIdx.x] = 0;
}

// ---------------- KT: weight transpose+cvt: dst[n][k] = bf16(src[k][n]) ----------------
// two-source variant: z<8 -> (srcA,dstA,e=z), else (srcB,dstB,e=z-8)
__global__ __launch_bounds__(256) void kt_transpose2(const float* __restrict__ srcA,
                                                     u16* __restrict__ dstA,
                                                     const float* __restrict__ srcB,
                                                     u16* __restrict__ dstB, int K, int N) {
  __shared__ u16 t[64][72];
  int z = blockIdx.z;
  const float* src = (z < NE ? srcA : srcB) + (size_t)(z & 7) * K * N;
  u16* dst = (z < NE ? dstA : dstB) + (size_t)(z & 7) * K * N;
  int nb = blockIdx.x * 64, kb = blockIdx.y * 64;
  int tid = threadIdx.x;
  int lk = tid >> 4, ln = (tid & 15) * 4;
#pragma unroll
  for (int p = 0; p < 4; ++p) {
    int k = lk + 16 * p;
    float4 v = *(const float4*)(src + (size_t)(kb + k) * N + nb + ln);
    t[ln + 0][k] = f2bf(v.x);
    t[ln + 1][k] = f2bf(v.y);
    t[ln + 2][k] = f2bf(v.z);
    t[ln + 3][k] = f2bf(v.w);
  }
  __syncthreads();
  int n = tid >> 2, c = tid & 3;
  short8 o0 = *(const short8*)&t[n][c * 16];
  short8 o1 = *(const short8*)&t[n][c * 16 + 8];
  u16* d = dst + (size_t)(nb + n) * K + kb + c * 16;
  *(short8*)d = o0;
  *(short8*)(d + 8) = o1;
}

// ---------------- K1: router ----------------
__global__ __launch_bounds__(256) void k1_router(const float* __restrict__ x,
                                                 const float* __restrict__ wgate,
                                                 float* __restrict__ logits_out,
                                                 char* __restrict__ sel,
                                                 float* __restrict__ wt,
                                                 unsigned* __restrict__ cnt) {
  int wave = threadIdx.x >> 6;
  int lane = threadIdx.x & 63;
  int t = blockIdx.x * 4 + wave;
  float acc[NE];
#pragma unroll
  for (int e = 0; e < NE; ++e) acc[e] = 0.f;
  const float4* xr = (const float4*)(x + (size_t)t * HDIM);
#pragma unroll
  for (int c = 0; c < HDIM / 256; ++c) {
    float4 xv = xr[c * 64 + lane];
    int h = (c * 64 + lane) * 4;
    const float xs[4] = {xv.x, xv.y, xv.z, xv.w};
#pragma unroll
    for (int j = 0; j < 4; ++j) {
      const float* wrow = wgate + (size_t)(h + j) * NE;
#pragma unroll
      for (int e = 0; e < NE; ++e) acc[e] += xs[j] * wrow[e];
    }
  }
#pragma unroll
  for (int e = 0; e < NE; ++e) {
    float v = acc[e];
#pragma unroll
    for (int off = 32; off; off >>= 1) v += __shfl_xor(v, off, 64);
    acc[e] = v;
  }
  if (lane == 0) {
    float m = acc[0];
#pragma unroll
    for (int e = 0; e < NE; ++e) {
      logits_out[(size_t)t * NE + e] = acc[e];
      m = fmaxf(m, acc[e]);
    }
    float p[NE];
#pragma unroll
    for (int e = 0; e < NE; ++e) p[e] = expf(acc[e] - m);
    int b0 = 0;
    float v0 = p[0];
#pragma unroll
    for (int e = 1; e < NE; ++e)
      if (p[e] > v0) { v0 = p[e]; b0 = e; }
    int b1 = -1;
    float v1 = -1.f;
#pragma unroll
    for (int e = 0; e < NE; ++e)
      if (e != b0 && p[e] > v1) { v1 = p[e]; b1 = e; }
    float denom = v0 + v1;
    sel[t * 2 + 0] = (char)b0;
    sel[t * 2 + 1] = (char)b1;
    wt[t * 2 + 0] = v0 / denom;
    wt[t * 2 + 1] = v1 / denom;
    atomicAdd(&cnt[b0], 1u);
    atomicAdd(&cnt[b1], 1u);
  }
}

// ---------------- K2 / K3 ----------------
__global__ void k2_prefix(const unsigned* __restrict__ cnt, unsigned* __restrict__ offsets,
                          unsigned* __restrict__ cursor) {
  if (threadIdx.x == 0) {
    unsigned s = 0;
    for (int e = 0; e < NE; ++e) {
      offsets[e] = s;
      s += cnt[e];
    }
  }
  if (threadIdx.x < NE) cursor[threadIdx.x] = 0;
}

__global__ __launch_bounds__(256) void k3_assign(const char* __restrict__ sel,
                                                 const float* __restrict__ wt,
                                                 const unsigned* __restrict__ offsets,
                                                 unsigned* __restrict__ cursor,
                                                 u16* __restrict__ slot_token,
                                                 float* __restrict__ slot_w,
                                                 u16* __restrict__ tok2slot) {
  int t = blockIdx.x * 256 + threadIdx.x;
#pragma unroll
  for (int k = 0; k < 2; ++k) {
    int e = sel[t * 2 + k];
    unsigned p = atomicAdd(&cursor[e], 1u);
    unsigned s = offsets[e] + p;
    slot_token[s] = (u16)t;
    slot_w[s] = wt[t * 2 + k];
    tok2slot[t * 2 + k] = (u16)s;
  }
}

// Bijective XCD swizzle for 64x8x8 = 4096-block grids (8 XCDs, 512/XCD).
__device__ inline void xcd_decomp(int& bx, int& by, int& be) {
  unsigned bid = blockIdx.x + 64u * (blockIdx.y + 8u * blockIdx.z);
  unsigned swz = (bid & 7u) * 512u + (bid >> 3);
  bx = swz & 63u;
  unsigned rem = swz >> 6;
  by = rem & 7u;
  be = rem >> 3;
}

// ---------------- K4: MFMA gate+up + silu -> bf16 act ----------------
// tile 128m x 128n, 4 waves (64x64 each), BK=32, ring-3 LDS (72 KB),
// depth-2 prefetch, 6 gl_lds/wave/iter, counted vmcnt. 32 MFMA/wave/iter.
__global__ __launch_bounds__(256, 2) void k4_gateup(
    const u16* __restrict__ xb, const u16* __restrict__ wgT, const u16* __restrict__ wuT,
    const u16* __restrict__ slot_token, const unsigned* __restrict__ offsets,
    const unsigned* __restrict__ cnt, u16* __restrict__ act) {
  int bx, by, e;
  xcd_decomp(bx, by, e);
  unsigned n = cnt[e];
  unsigned row0 = (unsigned)bx * 128;
  if (row0 >= n) return;
  unsigned base = offsets[e];
  int col0 = by * 128;

  __shared__ __align__(16) u16 As[3][128 * 32];  // 24 KB
  __shared__ __align__(16) u16 Bg[3][128 * 32];  // 24 KB
  __shared__ __align__(16) u16 Bu[3][128 * 32];  // 24 KB

  int tid = threadIdx.x;
  int w = tid >> 6, l = tid & 63;
  int wr = w >> 1, wc = w & 1;
  int lr = l & 15, g = l >> 4;

  // A: 2 gl_lds/wave (16 rows each), gathered rows
  const u16* asrc[2];
  int adst[2];
#pragma unroll
  for (int i = 0; i < 2; ++i) {
    int r = 32 * w + 16 * i + (l >> 2);
    unsigned grow = row0 + (unsigned)r;
    unsigned slot = base + (grow < n ? grow : 0);
    int chunk = (l & 3) ^ ((r >> 1) & 3);
    asrc[i] = xb + (size_t)slot_token[slot] * HDIM + 8 * chunk;
    adst[i] = (32 * w + 16 * i) * 32;
  }
  // B: 2 gl_lds/wave per matrix (n-rows 32w..32w+31)
  const u16* bgsrc[2];
  const u16* busrc[2];
  int bdst[2];
#pragma unroll
  for (int i = 0; i < 2; ++i) {
    int nn = 32 * w + 16 * i + (l >> 2);
    int chunk = (l & 3) ^ ((nn >> 1) & 3);
    size_t o = (size_t)e * HDIM * IDIM + (size_t)(col0 + nn) * HDIM + 8 * chunk;
    bgsrc[i] = wgT + o;
    busrc[i] = wuT + o;
    bdst[i] = (32 * w + 16 * i) * 32;
  }

  int afo[4], bfo[4];
#pragma unroll
  for (int mf = 0; mf < 4; ++mf) afo[mf] = rswz(wr * 64 + mf * 16 + lr, g);
#pragma unroll
  for (int nf = 0; nf < 4; ++nf) bfo[nf] = rswz(wc * 64 + nf * 16 + lr, g);

  f32x4 accg[4][4] = {};
  f32x4 accu[4][4] = {};

#define K4_STAGE(k0, buf)                           \
  do {                                              \
    gl_lds(asrc[0] + (k0), &As[buf][adst[0]]);      \
    gl_lds(asrc[1] + (k0), &As[buf][adst[1]]);      \
    gl_lds(bgsrc[0] + (k0), &Bg[buf][bdst[0]]);     \
    gl_lds(bgsrc[1] + (k0), &Bg[buf][bdst[1]]);     \
    gl_lds(busrc[0] + (k0), &Bu[buf][bdst[0]]);     \
    gl_lds(busrc[1] + (k0), &Bu[buf][bdst[1]]);     \
  } while (0)

  K4_STAGE(0, 0);
  K4_STAGE(32, 1);  // 12 loads in flight

  const int NK = HDIM / 32;
  int c = 0, sb = 2;
  for (int kt = 0; kt < NK; ++kt) {
    if (kt + 2 < NK) {
      K4_STAGE((kt + 2) * 32, sb);                       // 18 in flight
      asm volatile("s_waitcnt vmcnt(12)" ::: "memory");  // tile kt landed
    } else if (kt + 1 < NK) {
      asm volatile("s_waitcnt vmcnt(6)" ::: "memory");
    } else {
      asm volatile("s_waitcnt vmcnt(0)" ::: "memory");
    }
    __builtin_amdgcn_s_barrier();

    short8 af[4];
#pragma unroll
    for (int mf = 0; mf < 4; ++mf) af[mf] = *(const short8*)&As[c][afo[mf]];
#pragma unroll
    for (int nf = 0; nf < 4; ++nf) {
      short8 bgf = *(const short8*)&Bg[c][bfo[nf]];
      short8 buf = *(const short8*)&Bu[c][bfo[nf]];
#pragma unroll
      for (int mf = 0; mf < 4; ++mf) {
        accg[mf][nf] = __builtin_amdgcn_mfma_f32_16x16x32_bf16(af[mf], bgf, accg[mf][nf], 0, 0, 0);
        accu[mf][nf] = __builtin_amdgcn_mfma_f32_16x16x32_bf16(af[mf], buf, accu[mf][nf], 0, 0, 0);
      }
    }
    __builtin_amdgcn_s_barrier();
    c = (c == 2) ? 0 : c + 1;
    sb = (sb == 2) ? 0 : sb + 1;
  }
#undef K4_STAGE

  unsigned rows_left = n - row0;
#pragma unroll
  for (int mf = 0; mf < 4; ++mf)
#pragma unroll
    for (int nf = 0; nf < 4; ++nf)
#pragma unroll
      for (int j = 0; j < 4; ++j) {
        int rin = wr * 64 + mf * 16 + 4 * g + j;
        if ((unsigned)rin < rows_left) {
          size_t s = base + row0 + rin;
          int col = col0 + wc * 64 + nf * 16 + lr;
          float gg = accg[mf][nf][j];
          float uu = accu[mf][nf][j];
          float v = (gg / (1.f + expf(-gg))) * uu;
          act[s * IDIM + col] = f2bf(v);
        }
      }
}

// ---------------- K5: MFMA down -> bf16 y (no atomics) ----------------
// tile 128m x 256n, 4 waves (64x128 each), BK=32, ring-3 LDS (72 KB),
// depth-2 prefetch, 6 gl_lds/wave/iter. 32 MFMA/wave/iter.
__global__ __launch_bounds__(256, 2) void k5_down(
    const u16* __restrict__ act, const u16* __restrict__ wdT,
    const unsigned* __restrict__ offsets, const unsigned* __restrict__ cnt,
    u16* __restrict__ y) {
  int bx, by, e;
  xcd_decomp(bx, by, e);
  unsigned n = cnt[e];
  unsigned row0 = (unsigned)bx * 128;
  if (row0 >= n) return;
  unsigned base = offsets[e];
  int col0 = by * 256;

  __shared__ __align__(16) u16 As[3][128 * 32];  // 24 KB
  __shared__ __align__(16) u16 Bs[3][256 * 32];  // 48 KB

  int tid = threadIdx.x;
  int w = tid >> 6, l = tid & 63;
  int wr = w >> 1, wc = w & 1;
  int lr = l & 15, g = l >> 4;

  const u16* asrc[2];
  int adst[2];
#pragma unroll
  for (int i = 0; i < 2; ++i) {
    int r = 32 * w + 16 * i + (l >> 2);
    unsigned grow = row0 + (unsigned)r;
    unsigned slot = base + (grow < n ? grow : 0);
    int chunk = (l & 3) ^ ((r >> 1) & 3);
    asrc[i] = act + (size_t)slot * IDIM + 8 * chunk;
    adst[i] = (32 * w + 16 * i) * 32;
  }
  const u16* bsrc[4];
  int bdst[4];
#pragma unroll
  for (int i = 0; i < 4; ++i) {
    int nn = 64 * w + 16 * i + (l >> 2);
    int chunk = (l & 3) ^ ((nn >> 1) & 3);
    bsrc[i] = wdT + (size_t)e * IDIM * HDIM + (size_t)(col0 + nn) * IDIM + 8 * chunk;
    bdst[i] = (64 * w + 16 * i) * 32;
  }

  int afo[4], bfo[8];
#pragma unroll
  for (int mf = 0; mf < 4; ++mf) afo[mf] = rswz(wr * 64 + mf * 16 + lr, g);
#pragma unroll
  for (int nf = 0; nf < 8; ++nf) bfo[nf] = rswz(wc * 128 + nf * 16 + lr, g);

  f32x4 acc[4][8] = {};

#define K5_STAGE(k0, buf)                        \
  do {                                           \
    gl_lds(asrc[0] + (k0), &As[buf][adst[0]]);   \
    gl_lds(asrc[1] + (k0), &As[buf][adst[1]]);   \
    gl_lds(bsrc[0] + (k0), &Bs[buf][bdst[0]]);   \
    gl_lds(bsrc[1] + (k0), &Bs[buf][bdst[1]]);   \
    gl_lds(bsrc[2] + (k0), &Bs[buf][bdst[2]]);   \
    gl_lds(bsrc[3] + (k0), &Bs[buf][bdst[3]]);   \
  } while (0)

  K5_STAGE(0, 0);
  K5_STAGE(32, 1);

  const int NK = IDIM / 32;
  int c = 0, sb = 2;
  for (int kt = 0; kt < NK; ++kt) {
    if (kt + 2 < NK) {
      K5_STAGE((kt + 2) * 32, sb);
      asm volatile("s_waitcnt vmcnt(12)" ::: "memory");
    } else if (kt + 1 < NK) {
      asm volatile("s_waitcnt vmcnt(6)" ::: "memory");
    } else {
      asm volatile("s_waitcnt vmcnt(0)" ::: "memory");
    }
    __builtin_amdgcn_s_barrier();

    short8 af[4];
#pragma unroll
    for (int mf = 0; mf < 4; ++mf) af[mf] = *(const short8*)&As[c][afo[mf]];
#pragma unroll
    for (int nf = 0; nf < 8; ++nf) {
      short8 bd = *(const short8*)&Bs[c][bfo[nf]];
#pragma unroll
      for (int mf = 0; mf < 4; ++mf)
        acc[mf][nf] = __builtin_amdgcn_mfma_f32_16x16x32_bf16(af[mf], bd, acc[mf][nf], 0, 0, 0);
    }
    __builtin_amdgcn_s_barrier();
    c = (c == 2) ? 0 : c + 1;
    sb = (sb == 2) ? 0 : sb + 1;
  }
#undef K5_STAGE

  unsigned rows_left = n - row0;
#pragma unroll
  for (int mf = 0; mf < 4; ++mf)
#pragma unroll
    for (int j = 0; j < 4; ++j) {
      int rin = wr * 64 + mf * 16 + 4 * g + j;
      if ((unsigned)rin < rows_left) {
        size_t s = base + row0 + rin;
        u16* yrow = y + s * HDIM + col0 + wc * 128 + lr;
#pragma unroll
        for (int nf = 0; nf < 8; ++nf) yrow[nf * 16] = f2bf(acc[mf][nf][j]);
      }
    }
}

// ---------------- K6: combine out[t] = w0*y[s0] + w1*y[s1] ----------------
__global__ __launch_bounds__(256) void k6_combine(const u16* __restrict__ y,
                                                  const u16* __restrict__ tok2slot,
                                                  const float* __restrict__ slot_w,
                                                  float* __restrict__ out) {
  unsigned idx = blockIdx.x * 256 + threadIdx.x;  // one per 8 elems
  int t = idx >> 8;                               // HDIM/8 = 256 chunks per row
  int off = (idx & 255) * 8;
  int s0 = tok2slot[t * 2 + 0];
  int s1 = tok2slot[t * 2 + 1];
  float w0 = slot_w[s0];
  float w1 = slot_w[s1];
  short8 a = *(const short8*)(y + (size_t)s0 * HDIM + off);
  short8 b = *(const short8*)(y + (size_t)s1 * HDIM + off);
  float* o = out + (size_t)t * HDIM + off;
  float4 o0, o1;
  o0.x = w0 * bf2f((u16)a[0]) + w1 * bf2f((u16)b[0]);
  o0.y = w0 * bf2f((u16)a[1]) + w1 * bf2f((u16)b[1]);
  o0.z = w0 * bf2f((u16)a[2]) + w1 * bf2f((u16)b[2]);
  o0.w = w0 * bf2f((u16)a[3]) + w1 * bf2f((u16)b[3]);
  o1.x = w0 * bf2f((u16)a[4]) + w1 * bf2f((u16)b[4]);
  o1.y = w0 * bf2f((u16)a[5]) + w1 * bf2f((u16)b[5]);
  o1.z = w0 * bf2f((u16)a[6]) + w1 * bf2f((u16)b[6]);
  o1.w = w0 * bf2f((u16)a[7]) + w1 * bf2f((u16)b[7]);
  *(float4*)o = o0;
  *(float4*)(o + 4) = o1;
}

extern "C" void kernel_launch(void* const* d_in, const int* in_sizes, int n_in,
                              void* d_out, int out_size, void* d_ws, size_t ws_size,
                              hipStream_t stream) {
  const float* x = (const float*)d_in[0];
  const float* wgate = (const float*)d_in[1];
  const float* wg = (const float*)d_in[2];
  const float* wu = (const float*)d_in[3];
  const float* wd = (const float*)d_in[4];
  float* out = (float*)d_out;
  float* logits = out + (size_t)T_TOK * HDIM;

  const size_t XBF_OFF = 132096;
  const size_t ACT_OFF = XBF_OFF + (size_t)T_TOK * HDIM * 2;       // 33,686,528
  const size_t WGT_OFF = ACT_OFF + (size_t)2 * T_TOK * IDIM * 2;   // 67,240,960
  const size_t WUT_OFF = WGT_OFF + (size_t)NE * HDIM * IDIM * 2;   // 100,795,392
  const size_t WDT_OFF = WUT_OFF + (size_t)NE * HDIM * IDIM * 2;   // 134,349,824
  const size_t NEED_T3 = WDT_OFF + (size_t)NE * IDIM * HDIM * 2;   // 167,904,256 (proven R5)
  if (ws_size < NEED_T3) return;  // loud failure

  char* ws = (char*)d_ws;
  unsigned* meta = (unsigned*)ws;
  unsigned* cnt = meta + 0;
  unsigned* cursor = meta + 8;
  unsigned* offsets = meta + 16;
  u16* slot_token = (u16*)(ws + 256);     // 32 KB
  float* slot_w = (float*)(ws + 33024);   // 64 KB
  u16* tok2slot = (u16*)(ws + 98560);     // 32 KB -> ends 131328
  u16* xbf = (u16*)(ws + XBF_OFF);
  u16* act = (u16*)(ws + ACT_OFF);
  u16* wgT = (u16*)(ws + WGT_OFF);
  u16* wuT = (u16*)(ws + WUT_OFF);
  u16* wdT = (u16*)(ws + WDT_OFF);
  u16* y = (u16*)(ws + WGT_OFF);          // reuses wgT+wuT (dead after k4); 67 MB exact
  char* sel = (char*)act;                 // dead before k4 writes act
  float* wt = (float*)((char*)act + 16384);

  k0_init<<<2048, 256, 0, stream>>>(x, xbf, meta);
  kt_transpose2<<<dim3(IDIM / 64, HDIM / 64, 2 * NE), 256, 0, stream>>>(wg, wgT, wu, wuT,
                                                                        HDIM, IDIM);
  kt_transpose2<<<dim3(HDIM / 64, IDIM / 64, NE), 256, 0, stream>>>(wd, wdT, wd, wdT,
                                                                    IDIM, HDIM);
  k1_router<<<T_TOK / 4, 256, 0, stream>>>(x, wgate, logits, sel, wt, cnt);
  k2_prefix<<<1, 64, 0, stream>>>(cnt, offsets, cursor);
  k3_assign<<<T_TOK / 256, 256, 0, stream>>>(sel, wt, offsets, cursor, slot_token, slot_w,
                                             tok2slot);
  k4_gateup<<<dim3(T_TOK / 128, IDIM / 128, NE), 256, 0, stream>>>(xbf, wgT, wuT, slot_token,
                                                                   offsets, cnt, act);
  k5_down<<<dim3(T_TOK / 128, HDIM / 256, NE), 256, 0, stream>>>(act, wdT, offsets, cnt, y);
  k6_combine<<<T_TOK * HDIM / 8 / 256, 256, 0, stream>>>(y, tok2slot, slot_w, out);
}